// Round 1
// baseline (554.962 us; speedup 1.0000x reference)
//
#include <hip/hip_runtime.h>
#include <stdint.h>

typedef float f32x4 __attribute__((ext_vector_type(4)));
typedef short bf16x8 __attribute__((ext_vector_type(8)));
typedef unsigned short u16;

__device__ __forceinline__ u16 f2bf(float f) {
    union { float f; uint32_t u; } v; v.f = f;
    uint32_t r = v.u + 0x7FFFu + ((v.u >> 16) & 1u);
    return (u16)(r >> 16);
}
__device__ __forceinline__ float bf2f(u16 b) {
    union { uint32_t u; float f; } v; v.u = ((uint32_t)b) << 16;
    return v.f;
}

#define BK 32
#define LDS_STRIDE 40

// C[M][N] = A[M][K] @ Bt[N][K]^T, optional scale, bf16 or f32 C.
// A is f32 (converted to bf16 during staging) or bf16.
template<bool A_F32, bool C_BF16, bool SCALE>
__global__ __launch_bounds__(256)
void gemm_bt(const void* __restrict__ Av, const u16* __restrict__ Bt,
             void* __restrict__ Cv, int M, int N, int K, float scale)
{
    __shared__ u16 a_s[128 * LDS_STRIDE];
    __shared__ u16 b_s[128 * LDS_STRIDE];
    const int tid  = threadIdx.x;
    const int bm   = blockIdx.y * 128;
    const int bn   = blockIdx.x * 128;
    const int lane = tid & 63;
    const int wid  = tid >> 6;
    const int lr   = lane & 15;
    const int kg   = lane >> 4;
    const int wm   = (wid >> 1) * 64;
    const int wn   = (wid & 1) * 64;
    const int srow = tid >> 1;   // 0..127
    const int kh   = tid & 1;    // which 16-wide k half

    f32x4 acc[4][4];
#pragma unroll
    for (int i = 0; i < 4; ++i)
#pragma unroll
        for (int j = 0; j < 4; ++j)
            acc[i][j] = (f32x4){0.f, 0.f, 0.f, 0.f};

    for (int k0 = 0; k0 < K; k0 += BK) {
        __syncthreads();
        // ---- stage A tile (128 x 32) ----
        {
            u16* dst = &a_s[srow * LDS_STRIDE + kh * 16];
            if constexpr (A_F32) {
                const float* src = (const float*)Av + (size_t)(bm + srow) * K + k0 + kh * 16;
                float t[16];
                *(float4*)&t[0]  = *(const float4*)(src + 0);
                *(float4*)&t[4]  = *(const float4*)(src + 4);
                *(float4*)&t[8]  = *(const float4*)(src + 8);
                *(float4*)&t[12] = *(const float4*)(src + 12);
                bf16x8 w0, w1;
#pragma unroll
                for (int j = 0; j < 8; ++j) {
                    w0[j] = (short)f2bf(t[j]);
                    w1[j] = (short)f2bf(t[8 + j]);
                }
                *(bf16x8*)dst       = w0;
                *(bf16x8*)(dst + 8) = w1;
            } else {
                const u16* src = (const u16*)Av + (size_t)(bm + srow) * K + k0 + kh * 16;
                *(bf16x8*)dst       = *(const bf16x8*)src;
                *(bf16x8*)(dst + 8) = *(const bf16x8*)(src + 8);
            }
        }
        // ---- stage B tile (128 x 32) from Bt[N][K] ----
        {
            const u16* src = Bt + (size_t)(bn + srow) * K + k0 + kh * 16;
            u16* dst = &b_s[srow * LDS_STRIDE + kh * 16];
            *(bf16x8*)dst       = *(const bf16x8*)src;
            *(bf16x8*)(dst + 8) = *(const bf16x8*)(src + 8);
        }
        __syncthreads();

        bf16x8 af[4], bfr[4];
#pragma unroll
        for (int i = 0; i < 4; ++i)
            af[i] = *(const bf16x8*)&a_s[(wm + i * 16 + lr) * LDS_STRIDE + kg * 8];
#pragma unroll
        for (int j = 0; j < 4; ++j)
            bfr[j] = *(const bf16x8*)&b_s[(wn + j * 16 + lr) * LDS_STRIDE + kg * 8];
#pragma unroll
        for (int i = 0; i < 4; ++i)
#pragma unroll
            for (int j = 0; j < 4; ++j)
                acc[i][j] = __builtin_amdgcn_mfma_f32_16x16x32_bf16(af[i], bfr[j], acc[i][j], 0, 0, 0);
    }

    // ---- epilogue: C/D layout col=lane&15, row=(lane>>4)*4+reg (m89-verified) ----
    const int r0 = kg * 4;
#pragma unroll
    for (int i = 0; i < 4; ++i) {
#pragma unroll
        for (int j = 0; j < 4; ++j) {
            const int col = bn + wn + j * 16 + lr;
#pragma unroll
            for (int r = 0; r < 4; ++r) {
                const int row = bm + wm + i * 16 + r0 + r;
                float v = acc[i][j][r];
                if constexpr (SCALE) v *= scale;
                if constexpr (C_BF16)
                    ((u16*)Cv)[(size_t)row * N + col] = f2bf(v);
                else
                    ((float*)Cv)[(size_t)row * N + col] = v;
            }
        }
    }
}

// out[c][r] = bf16(in[r][c]); in is [R][C] (f32 or bf16), out is [C][R] bf16.
template<bool IN_F32>
__global__ __launch_bounds__(256)
void transpose_to_bf16(const void* __restrict__ in_v, u16* __restrict__ out, int R, int C)
{
    __shared__ u16 tile[64][65];
    const int r0 = blockIdx.y * 64;
    const int c0 = blockIdx.x * 64;
    const int tr = threadIdx.x >> 2;  // 0..63
    const int tq = threadIdx.x & 3;   // 0..3 (16 elems each)

    if constexpr (IN_F32) {
        const float* in = (const float*)in_v + (size_t)(r0 + tr) * C + c0 + tq * 16;
#pragma unroll
        for (int i = 0; i < 16; i += 4) {
            float4 v = *(const float4*)(in + i);
            tile[tq * 16 + i + 0][tr] = f2bf(v.x);
            tile[tq * 16 + i + 1][tr] = f2bf(v.y);
            tile[tq * 16 + i + 2][tr] = f2bf(v.z);
            tile[tq * 16 + i + 3][tr] = f2bf(v.w);
        }
    } else {
        const u16* in = (const u16*)in_v + (size_t)(r0 + tr) * C + c0 + tq * 16;
#pragma unroll
        for (int i = 0; i < 16; i += 8) {
            bf16x8 v = *(const bf16x8*)(in + i);
#pragma unroll
            for (int j = 0; j < 8; ++j) tile[tq * 16 + i + j][tr] = (u16)v[j];
        }
    }
    __syncthreads();

    u16 tmp[16];
#pragma unroll
    for (int i = 0; i < 16; ++i) tmp[i] = tile[tr][tq * 16 + i];
    bf16x8 w0, w1;
#pragma unroll
    for (int j = 0; j < 8; ++j) { w0[j] = (short)tmp[j]; w1[j] = (short)tmp[8 + j]; }
    u16* o = out + (size_t)(c0 + tr) * R + r0 + tq * 16;
    *(bf16x8*)o       = w0;
    *(bf16x8*)(o + 8) = w1;
}

// In-place row softmax over bf16 logits: one block per row of 8192.
__global__ __launch_bounds__(256)
void softmax_inplace(u16* __restrict__ att)
{
    const int tid = threadIdx.x;
    u16* p = att + (size_t)blockIdx.x * 8192;

    float x[32];
#pragma unroll
    for (int c = 0; c < 4; ++c) {
        bf16x8 v = *(const bf16x8*)(p + c * 2048 + tid * 8);
#pragma unroll
        for (int j = 0; j < 8; ++j) x[c * 8 + j] = bf2f((u16)v[j]);
    }

    float mx = -1e30f;
#pragma unroll
    for (int i = 0; i < 32; ++i) mx = fmaxf(mx, x[i]);
#pragma unroll
    for (int o = 32; o >= 1; o >>= 1) mx = fmaxf(mx, __shfl_xor(mx, o));

    __shared__ float red[8];
    const int wid = tid >> 6, lane = tid & 63;
    if (lane == 0) red[wid] = mx;
    __syncthreads();
    mx = fmaxf(fmaxf(red[0], red[1]), fmaxf(red[2], red[3]));

    float s = 0.f;
#pragma unroll
    for (int i = 0; i < 32; ++i) { x[i] = __expf(x[i] - mx); s += x[i]; }
#pragma unroll
    for (int o = 32; o >= 1; o >>= 1) s += __shfl_xor(s, o);
    if (lane == 0) red[4 + wid] = s;
    __syncthreads();
    s = red[4] + red[5] + red[6] + red[7];
    const float inv = 1.0f / s;

#pragma unroll
    for (int c = 0; c < 4; ++c) {
        bf16x8 w;
#pragma unroll
        for (int j = 0; j < 8; ++j) w[j] = (short)f2bf(x[c * 8 + j] * inv);
        *(bf16x8*)(p + c * 2048 + tid * 8) = w;
    }
}

extern "C" void kernel_launch(void* const* d_in, const int* in_sizes, int n_in,
                              void* d_out, int out_size, void* d_ws, size_t ws_size,
                              hipStream_t stream)
{
    const float* host   = (const float*)d_in[0];  // [4096][1024]
    const float* guests = (const float*)d_in[1];  // [8192][1024]
    const float* Qw     = (const float*)d_in[2];  // [1024][1024]
    const float* Kw     = (const float*)d_in[3];
    const float* Vw     = (const float*)d_in[4];
    float* out = (float*)d_out;                   // [4096][1024]

    char* ws = (char*)d_ws;
    u16* query_bf = (u16*)(ws + (0ull   << 20));  // 4096x1024 bf16,  8MB
    u16* key_bf   = (u16*)(ws + (8ull   << 20));  // 8192x1024 bf16, 16MB
    u16* value_bf = (u16*)(ws + (24ull  << 20));  // 8192x1024 bf16, 16MB
    u16* value_t  = (u16*)(ws + (40ull  << 20));  // 1024x8192 bf16, 16MB
    u16* Qt       = (u16*)(ws + (56ull  << 20));  // 1024x1024 bf16,  2MB
    u16* Kt       = (u16*)(ws + (58ull  << 20));
    u16* Vt       = (u16*)(ws + (60ull  << 20));
    u16* att      = (u16*)(ws + (62ull  << 20));  // 4096x8192 bf16, 64MB (ends @126MB)

    dim3 blk(256);

    // Weight transposes: Wt[n][k] = bf16(W[k][n])
    transpose_to_bf16<true><<<dim3(16, 16), blk, 0, stream>>>(Qw, Qt, 1024, 1024);
    transpose_to_bf16<true><<<dim3(16, 16), blk, 0, stream>>>(Kw, Kt, 1024, 1024);
    transpose_to_bf16<true><<<dim3(16, 16), blk, 0, stream>>>(Vw, Vt, 1024, 1024);

    // Projections (A f32 -> bf16 staged), C bf16
    gemm_bt<true, true, false><<<dim3(8, 32), blk, 0, stream>>>(host,   Qt, query_bf, 4096, 1024, 1024, 1.f);
    gemm_bt<true, true, false><<<dim3(8, 64), blk, 0, stream>>>(guests, Kt, key_bf,   8192, 1024, 1024, 1.f);
    gemm_bt<true, true, false><<<dim3(8, 64), blk, 0, stream>>>(guests, Vt, value_bf, 8192, 1024, 1024, 1.f);

    // value_t[d][m] = value_bf[m][d]
    transpose_to_bf16<false><<<dim3(16, 128), blk, 0, stream>>>(value_bf, value_t, 8192, 1024);

    // att[q][m] = (query . key) / 32, bf16
    gemm_bt<false, true, true><<<dim3(64, 32), blk, 0, stream>>>(query_bf, key_bf, att, 4096, 8192, 1024, 0.03125f);

    // softmax rows (in place)
    softmax_inplace<<<dim3(4096), blk, 0, stream>>>(att);

    // out[q][d] = P @ value = att[q][m] * value_t[d][m]
    gemm_bt<false, false, false><<<dim3(8, 32), blk, 0, stream>>>(att, value_t, out, 4096, 1024, 8192, 1.f);
}

// Round 2
// 440.188 us; speedup vs baseline: 1.2607x; 1.2607x over previous
//
#include <hip/hip_runtime.h>
#include <stdint.h>

typedef float f32x4 __attribute__((ext_vector_type(4)));
typedef short bf16x8 __attribute__((ext_vector_type(8)));
typedef unsigned short u16;

__device__ __forceinline__ u16 f2bf(float f) {
    union { float f; uint32_t u; } v; v.f = f;
    uint32_t r = v.u + 0x7FFFu + ((v.u >> 16) & 1u);
    return (u16)(r >> 16);
}
__device__ __forceinline__ float bf2f(u16 b) {
    union { uint32_t u; float f; } v; v.u = ((uint32_t)b) << 16;
    return v.f;
}

// async global->LDS, 16 bytes per lane. LDS dest must be wave-uniform base;
// HW writes lane i at base + i*16.
__device__ __forceinline__ void gload16(u16* lds, const u16* g) {
    __builtin_amdgcn_global_load_lds(
        (const __attribute__((address_space(1))) void*)(uintptr_t)g,
        (__attribute__((address_space(3))) void*)(uint32_t)(uintptr_t)lds,
        16, 0, 0);
}

#define BK 32

// C[M][N] = A[M][K] @ Bt[N][K]^T. All-bf16 inputs, global_load_lds staging,
// linear LDS (m97 structure). Optional K-split across blockIdx.z (partials
// to C0/C1), optional scale, bf16 or f32 C.
template<bool C_BF16, bool SCALE, bool SPLIT>
__global__ __launch_bounds__(256)
void gemm_bt(const u16* __restrict__ A, const u16* __restrict__ Bt,
             void* __restrict__ C0, void* __restrict__ C1,
             int M, int N, int K, int lda, int ldb, int ldc,
             int kChunk, float scale)
{
    __shared__ u16 a_s[128 * BK];
    __shared__ u16 b_s[128 * BK];
    const int tid  = threadIdx.x;
    const int bm   = blockIdx.y * 128;
    const int bn   = blockIdx.x * 128;
    const int lane = tid & 63;
    const int wid  = tid >> 6;
    const int lr   = lane & 15;
    const int kg   = lane >> 4;
    const int wm   = (wid >> 1) * 64;
    const int wn   = (wid & 1) * 64;

    // staging: call c covers rows c*64..c*64+63; thread handles row tid/4,
    // col (tid&3)*8; wave-uniform LDS base = c*2048 + wid*512 (u16 units).
    const int srow = tid >> 2;        // 0..63
    const int scol = (tid & 3) * 8;

    int kBeg = 0, kEnd = K;
    void* Cv = C0;
    if constexpr (SPLIT) {
        kBeg = blockIdx.z * kChunk;
        kEnd = kBeg + kChunk; if (kEnd > K) kEnd = K;
        Cv = blockIdx.z ? C1 : C0;
    }

    const u16* Ar0 = A  + (size_t)(bm + srow) * lda + scol;
    const u16* Ar1 = A  + (size_t)(bm + 64 + srow) * lda + scol;
    const u16* Br0 = Bt + (size_t)(bn + srow) * ldb + scol;
    const u16* Br1 = Bt + (size_t)(bn + 64 + srow) * ldb + scol;
    u16* a_d0 = a_s + wid * 512;
    u16* a_d1 = a_s + 2048 + wid * 512;
    u16* b_d0 = b_s + wid * 512;
    u16* b_d1 = b_s + 2048 + wid * 512;

    f32x4 acc[4][4];
#pragma unroll
    for (int i = 0; i < 4; ++i)
#pragma unroll
        for (int j = 0; j < 4; ++j)
            acc[i][j] = (f32x4){0.f, 0.f, 0.f, 0.f};

    for (int k0 = kBeg; k0 < kEnd; k0 += BK) {
        __syncthreads();
        gload16(a_d0, Ar0 + k0);
        gload16(a_d1, Ar1 + k0);
        gload16(b_d0, Br0 + k0);
        gload16(b_d1, Br1 + k0);
        __syncthreads();   // compiler emits vmcnt(0) drain before barrier

        bf16x8 af[4], bfr[4];
#pragma unroll
        for (int i = 0; i < 4; ++i)
            af[i] = *(const bf16x8*)&a_s[(wm + i * 16 + lr) * BK + kg * 8];
#pragma unroll
        for (int j = 0; j < 4; ++j)
            bfr[j] = *(const bf16x8*)&b_s[(wn + j * 16 + lr) * BK + kg * 8];
#pragma unroll
        for (int i = 0; i < 4; ++i)
#pragma unroll
            for (int j = 0; j < 4; ++j)
                acc[i][j] = __builtin_amdgcn_mfma_f32_16x16x32_bf16(af[i], bfr[j], acc[i][j], 0, 0, 0);
    }

    // epilogue: C/D layout col=lane&15, row=(lane>>4)*4+reg (m89-verified)
    const int r0 = kg * 4;
#pragma unroll
    for (int i = 0; i < 4; ++i) {
#pragma unroll
        for (int j = 0; j < 4; ++j) {
            const int col = bn + wn + j * 16 + lr;
#pragma unroll
            for (int r = 0; r < 4; ++r) {
                const int row = bm + wm + i * 16 + r0 + r;
                float v = acc[i][j][r];
                if constexpr (SCALE) v *= scale;
                if constexpr (C_BF16)
                    ((u16*)Cv)[(size_t)row * ldc + col] = f2bf(v);
                else
                    ((float*)Cv)[(size_t)row * ldc + col] = v;
            }
        }
    }
}

// out[c*ldout + r] = bf16(in[r*ldin + c]); grid (Ctiles, Rtiles), 64x64 tiles.
template<bool IN_F32>
__global__ __launch_bounds__(256)
void transpose_to_bf16(const void* __restrict__ in_v, u16* __restrict__ out,
                       int ldin, int ldout)
{
    __shared__ u16 tile[64][65];
    const int r0 = blockIdx.y * 64;
    const int c0 = blockIdx.x * 64;
    const int tr = threadIdx.x >> 2;  // 0..63
    const int tq = threadIdx.x & 3;   // 0..3

    if constexpr (IN_F32) {
        const float* in = (const float*)in_v + (size_t)(r0 + tr) * ldin + c0 + tq * 16;
#pragma unroll
        for (int i = 0; i < 16; i += 4) {
            float4 v = *(const float4*)(in + i);
            tile[tq * 16 + i + 0][tr] = f2bf(v.x);
            tile[tq * 16 + i + 1][tr] = f2bf(v.y);
            tile[tq * 16 + i + 2][tr] = f2bf(v.z);
            tile[tq * 16 + i + 3][tr] = f2bf(v.w);
        }
    } else {
        const u16* in = (const u16*)in_v + (size_t)(r0 + tr) * ldin + c0 + tq * 16;
#pragma unroll
        for (int i = 0; i < 16; i += 8) {
            bf16x8 v = *(const bf16x8*)(in + i);
#pragma unroll
            for (int j = 0; j < 8; ++j) tile[tq * 16 + i + j][tr] = (u16)v[j];
        }
    }
    __syncthreads();

    u16 tmp[16];
#pragma unroll
    for (int i = 0; i < 16; ++i) tmp[i] = tile[tr][tq * 16 + i];
    bf16x8 w0, w1;
#pragma unroll
    for (int j = 0; j < 8; ++j) { w0[j] = (short)tmp[j]; w1[j] = (short)tmp[8 + j]; }
    u16* o = out + (size_t)(c0 + tr) * ldout + r0 + tq * 16;
    *(bf16x8*)o       = w0;
    *(bf16x8*)(o + 8) = w1;
}

// f32 -> bf16, 8 elems/thread, exact grid.
__global__ __launch_bounds__(256)
void cvt_f32_bf16(const float* __restrict__ in, u16* __restrict__ out)
{
    const size_t i = ((size_t)blockIdx.x * 256 + threadIdx.x) * 8;
    float4 v0 = *(const float4*)(in + i);
    float4 v1 = *(const float4*)(in + i + 4);
    bf16x8 w;
    w[0] = (short)f2bf(v0.x); w[1] = (short)f2bf(v0.y);
    w[2] = (short)f2bf(v0.z); w[3] = (short)f2bf(v0.w);
    w[4] = (short)f2bf(v1.x); w[5] = (short)f2bf(v1.y);
    w[6] = (short)f2bf(v1.z); w[7] = (short)f2bf(v1.w);
    *(bf16x8*)(out + i) = w;
}

// out += p (f32, float4 per thread, exact grid)
__global__ __launch_bounds__(256)
void add_f32(float* __restrict__ out, const float* __restrict__ p)
{
    const size_t i = ((size_t)blockIdx.x * 256 + threadIdx.x) * 4;
    float4 a = *(const float4*)(out + i);
    float4 b = *(const float4*)(p + i);
    a.x += b.x; a.y += b.y; a.z += b.z; a.w += b.w;
    *(float4*)(out + i) = a;
}

// In-place row softmax over bf16 logits: one block per row of 8192.
__global__ __launch_bounds__(256)
void softmax_inplace(u16* __restrict__ att)
{
    const int tid = threadIdx.x;
    u16* p = att + (size_t)blockIdx.x * 8192;

    float x[32];
#pragma unroll
    for (int c = 0; c < 4; ++c) {
        bf16x8 v = *(const bf16x8*)(p + c * 2048 + tid * 8);
#pragma unroll
        for (int j = 0; j < 8; ++j) x[c * 8 + j] = bf2f((u16)v[j]);
    }

    float mx = -1e30f;
#pragma unroll
    for (int i = 0; i < 32; ++i) mx = fmaxf(mx, x[i]);
#pragma unroll
    for (int o = 32; o >= 1; o >>= 1) mx = fmaxf(mx, __shfl_xor(mx, o));

    __shared__ float red[8];
    const int wid = tid >> 6, lane = tid & 63;
    if (lane == 0) red[wid] = mx;
    __syncthreads();
    mx = fmaxf(fmaxf(red[0], red[1]), fmaxf(red[2], red[3]));

    float s = 0.f;
#pragma unroll
    for (int i = 0; i < 32; ++i) { x[i] = __expf(x[i] - mx); s += x[i]; }
#pragma unroll
    for (int o = 32; o >= 1; o >>= 1) s += __shfl_xor(s, o);
    if (lane == 0) red[4 + wid] = s;
    __syncthreads();
    s = red[4] + red[5] + red[6] + red[7];
    const float inv = 1.0f / s;

#pragma unroll
    for (int c = 0; c < 4; ++c) {
        bf16x8 w;
#pragma unroll
        for (int j = 0; j < 8; ++j) w[j] = (short)f2bf(x[c * 8 + j] * inv);
        *(bf16x8*)(p + c * 2048 + tid * 8) = w;
    }
}

extern "C" void kernel_launch(void* const* d_in, const int* in_sizes, int n_in,
                              void* d_out, int out_size, void* d_ws, size_t ws_size,
                              hipStream_t stream)
{
    const float* host   = (const float*)d_in[0];  // [4096][1024]
    const float* guests = (const float*)d_in[1];  // [8192][1024]
    const float* Qw     = (const float*)d_in[2];  // [1024][1024]
    const float* Kw     = (const float*)d_in[3];
    const float* Vw     = (const float*)d_in[4];
    float* out = (float*)d_out;                   // [4096][1024]

    char* ws = (char*)d_ws;
    // Phase-overlapped layout (peak 120 MB):
    //   att      @  0..64MB  (QK^T..PV)   -- overlaps phase-1 temporaries:
    //     host_bf   @  0.. 8MB, guests_bf @ 8..24MB, Qt @24..26MB, KVt @26..30MB
    //     partial1  @  0..16MB (PV split-K, after att... no: partial overlaps att!)
    u16* att       = (u16*)(ws);                       // 4096x8192 bf16, 64MB
    u16* host_bf   = (u16*)(ws);                       // 4096x1024 bf16,  8MB (dead before att)
    u16* guests_bf = (u16*)(ws + ( 8ull << 20));       // 8192x1024 bf16, 16MB (dead before att)
    u16* Qt        = (u16*)(ws + (24ull << 20));       // 1024x1024 bf16,  2MB (dead before att)
    u16* KVt       = (u16*)(ws + (26ull << 20));       // 2048x1024 bf16,  4MB (dead before att)
    u16* value_t   = (u16*)(ws + (64ull << 20));       // 1024x8192 bf16, 16MB
    u16* query_bf  = (u16*)(ws + (80ull << 20));       // 4096x1024 bf16,  8MB
    u16* kv_bf     = (u16*)(ws + (88ull << 20));       // 8192x2048 bf16, 32MB
    float* part1   = (float*)(ws + (80ull << 20));     // 4096x1024 f32,  16MB (reuses query/kv region)

    dim3 blk(256);

    // ---- phase 1: dtype prep ----
    cvt_f32_bf16<<<dim3(2048), blk, 0, stream>>>(host,   host_bf);
    cvt_f32_bf16<<<dim3(4096), blk, 0, stream>>>(guests, guests_bf);
    transpose_to_bf16<true><<<dim3(16, 16), blk, 0, stream>>>(Qw, Qt,                1024, 1024);
    transpose_to_bf16<true><<<dim3(16, 16), blk, 0, stream>>>(Kw, KVt,               1024, 1024);
    transpose_to_bf16<true><<<dim3(16, 16), blk, 0, stream>>>(Vw, KVt + 1024 * 1024, 1024, 1024);

    // ---- phase 2: projections (all-bf16 GEMMs) ----
    // query = host @ Q : [4096][1024]
    gemm_bt<true, false, false><<<dim3(8, 32), blk, 0, stream>>>(
        host_bf, Qt, query_bf, query_bf, 4096, 1024, 1024, 1024, 1024, 1024, 0, 1.f);
    // kv = guests @ [K|V] : [8192][2048] (cols 0..1023 = key, 1024.. = value)
    gemm_bt<true, false, false><<<dim3(16, 64), blk, 0, stream>>>(
        guests_bf, KVt, kv_bf, kv_bf, 8192, 2048, 1024, 1024, 1024, 2048, 0, 1.f);

    // ---- phase 3: value transpose + QK^T ----
    // value_t[d][m] = kv_bf[m][1024+d]
    transpose_to_bf16<false><<<dim3(16, 128), blk, 0, stream>>>(
        kv_bf + 1024, value_t, 2048, 8192);
    // att[q][m] = (query . key) / 32
    gemm_bt<true, true, false><<<dim3(64, 32), blk, 0, stream>>>(
        query_bf, kv_bf, att, att, 4096, 8192, 1024, 1024, 2048, 8192, 0, 0.03125f);

    // ---- phase 4: softmax ----
    softmax_inplace<<<dim3(4096), blk, 0, stream>>>(att);

    // ---- phase 5: PV with split-K=2 (partial0 -> out, partial1 -> ws) ----
    gemm_bt<false, false, true><<<dim3(8, 32, 2), blk, 0, stream>>>(
        att, value_t, out, part1, 4096, 1024, 8192, 8192, 8192, 1024, 4096, 1.f);
    add_f32<<<dim3(4096), blk, 0, stream>>>(out, part1);
}

// Round 3
// 430.741 us; speedup vs baseline: 1.2884x; 1.0219x over previous
//
#include <hip/hip_runtime.h>
#include <stdint.h>

typedef float f32x4 __attribute__((ext_vector_type(4)));
typedef short bf16x8 __attribute__((ext_vector_type(8)));
typedef unsigned short u16;
typedef u16 u16x4 __attribute__((ext_vector_type(4)));

__device__ __forceinline__ u16 f2bf(float f) {
    union { float f; uint32_t u; } v; v.f = f;
    uint32_t r = v.u + 0x7FFFu + ((v.u >> 16) & 1u);
    return (u16)(r >> 16);
}
__device__ __forceinline__ float bf2f(u16 b) {
    union { uint32_t u; float f; } v; v.u = ((uint32_t)b) << 16;
    return v.f;
}

// async global->LDS, 16B/lane; LDS dest is wave-uniform base + lane*16.
__device__ __forceinline__ void gload16(u16* lds, const u16* g) {
    __builtin_amdgcn_global_load_lds(
        (const __attribute__((address_space(1))) void*)(uintptr_t)g,
        (__attribute__((address_space(3))) void*)(uint32_t)(uintptr_t)lds,
        16, 0, 0);
}

// XCD-aware chunked remap (bijective when nwg % 8 == 0): hw ids on the same
// XCD (stride-8) become consecutive logical tiles.
__device__ __forceinline__ int xcd_map(int bid, int nwg) {
    return (bid & 7) * (nwg >> 3) + (bid >> 3);
}

#define BK 32

// ---------------------------------------------------------------------------
// Merged projection GEMM: 128x128 tiles, K=1024, all-bf16.
//   group 0 (ids    0..255 ): query = host_bf @ Qt   -> query_bf row-major, *1/32
//   group 1 (ids  256..767 ): key   = guests  @ Kt   -> key_bf   row-major
//   group 2 (ids  768..1279): value = guests  @ Vt   -> value_t  TRANSPOSED [d][m]
// ---------------------------------------------------------------------------
__global__ __launch_bounds__(256)
void proj_gemm(const u16* __restrict__ host_bf, const u16* __restrict__ guests_bf,
               const u16* __restrict__ Qt, const u16* __restrict__ Kt,
               const u16* __restrict__ Vt,
               u16* __restrict__ query_bf, u16* __restrict__ key_bf,
               u16* __restrict__ value_t)
{
    __shared__ u16 a_s[128 * BK];
    __shared__ u16 b_s[128 * BK];
    const int id = xcd_map(blockIdx.x, 1280);

    const u16 *A, *B; u16* Crm = nullptr; int bm, bn; int group;
    if (id < 256)      { group = 0; A = host_bf;   B = Qt; Crm = query_bf; bm = (id >> 3) * 128;         bn = (id & 7) * 128; }
    else if (id < 768) { group = 1; A = guests_bf; B = Kt; Crm = key_bf;   bm = ((id - 256) >> 3) * 128; bn = ((id - 256) & 7) * 128; }
    else               { group = 2; A = guests_bf; B = Vt; Crm = nullptr;  bm = ((id - 768) >> 3) * 128; bn = ((id - 768) & 7) * 128; }

    const int tid  = threadIdx.x;
    const int lane = tid & 63;
    const int wid  = tid >> 6;
    const int lr   = lane & 15;
    const int kg   = lane >> 4;
    const int wm   = (wid >> 1) * 64;
    const int wn   = (wid & 1) * 64;
    const int srow = tid >> 2;
    const int scol = (tid & 3) * 8;

    const u16* Ar0 = A + (size_t)(bm + srow) * 1024 + scol;
    const u16* Ar1 = A + (size_t)(bm + 64 + srow) * 1024 + scol;
    const u16* Br0 = B + (size_t)(bn + srow) * 1024 + scol;
    const u16* Br1 = B + (size_t)(bn + 64 + srow) * 1024 + scol;
    u16* a_d0 = a_s + wid * 512;
    u16* a_d1 = a_s + 2048 + wid * 512;
    u16* b_d0 = b_s + wid * 512;
    u16* b_d1 = b_s + 2048 + wid * 512;

    f32x4 acc[4][4];
#pragma unroll
    for (int i = 0; i < 4; ++i)
#pragma unroll
        for (int j = 0; j < 4; ++j)
            acc[i][j] = (f32x4){0.f, 0.f, 0.f, 0.f};

    for (int k0 = 0; k0 < 1024; k0 += BK) {
        __syncthreads();
        gload16(a_d0, Ar0 + k0);
        gload16(a_d1, Ar1 + k0);
        gload16(b_d0, Br0 + k0);
        gload16(b_d1, Br1 + k0);
        __syncthreads();

        bf16x8 af[4], bfr[4];
#pragma unroll
        for (int i = 0; i < 4; ++i)
            af[i] = *(const bf16x8*)&a_s[(wm + i * 16 + lr) * BK + kg * 8];
#pragma unroll
        for (int j = 0; j < 4; ++j)
            bfr[j] = *(const bf16x8*)&b_s[(wn + j * 16 + lr) * BK + kg * 8];
#pragma unroll
        for (int i = 0; i < 4; ++i)
#pragma unroll
            for (int j = 0; j < 4; ++j)
                acc[i][j] = __builtin_amdgcn_mfma_f32_16x16x32_bf16(af[i], bfr[j], acc[i][j], 0, 0, 0);
    }

    // C/D layout (m89): col = lane&15, row = (lane>>4)*4 + reg
    const int r0 = kg * 4;
    if (group == 2) {
        // value transposed: value_t[d][m], d = col (0..1023), m = global row
#pragma unroll
        for (int i = 0; i < 4; ++i) {
#pragma unroll
            for (int j = 0; j < 4; ++j) {
                const int col = bn + wn + j * 16 + lr;
                const int row = bm + wm + i * 16 + r0;
                u16x4 w;
#pragma unroll
                for (int r = 0; r < 4; ++r) w[r] = f2bf(acc[i][j][r]);
                *(u16x4*)&value_t[(size_t)col * 8192 + row] = w;
            }
        }
    } else {
        const float scale = (group == 0) ? 0.03125f : 1.0f;
#pragma unroll
        for (int i = 0; i < 4; ++i) {
#pragma unroll
            for (int j = 0; j < 4; ++j) {
                const int col = bn + wn + j * 16 + lr;
#pragma unroll
                for (int r = 0; r < 4; ++r) {
                    const int row = bm + wm + i * 16 + r0 + r;
                    Crm[(size_t)row * 1024 + col] = f2bf(acc[i][j][r] * scale);
                }
            }
        }
    }
}

// ---------------------------------------------------------------------------
// QK^T: att[q][m] = query_bf[q][:] . key_bf[m][:]  (scale pre-folded into q)
// 128x128 tiles, grid 64x32, XCD swizzle, C bf16.
// ---------------------------------------------------------------------------
__global__ __launch_bounds__(256)
void qkt_gemm(const u16* __restrict__ A, const u16* __restrict__ Bt,
              u16* __restrict__ Cb)
{
    __shared__ u16 a_s[128 * BK];
    __shared__ u16 b_s[128 * BK];
    const int lin = blockIdx.x + (blockIdx.y << 6);
    const int swz = xcd_map(lin, 2048);
    const int bm = (swz >> 6) * 128;
    const int bn = (swz & 63) * 128;

    const int tid  = threadIdx.x;
    const int lane = tid & 63;
    const int wid  = tid >> 6;
    const int lr   = lane & 15;
    const int kg   = lane >> 4;
    const int wm   = (wid >> 1) * 64;
    const int wn   = (wid & 1) * 64;
    const int srow = tid >> 2;
    const int scol = (tid & 3) * 8;

    const u16* Ar0 = A  + (size_t)(bm + srow) * 1024 + scol;
    const u16* Ar1 = A  + (size_t)(bm + 64 + srow) * 1024 + scol;
    const u16* Br0 = Bt + (size_t)(bn + srow) * 1024 + scol;
    const u16* Br1 = Bt + (size_t)(bn + 64 + srow) * 1024 + scol;
    u16* a_d0 = a_s + wid * 512;
    u16* a_d1 = a_s + 2048 + wid * 512;
    u16* b_d0 = b_s + wid * 512;
    u16* b_d1 = b_s + 2048 + wid * 512;

    f32x4 acc[4][4];
#pragma unroll
    for (int i = 0; i < 4; ++i)
#pragma unroll
        for (int j = 0; j < 4; ++j)
            acc[i][j] = (f32x4){0.f, 0.f, 0.f, 0.f};

    for (int k0 = 0; k0 < 1024; k0 += BK) {
        __syncthreads();
        gload16(a_d0, Ar0 + k0);
        gload16(a_d1, Ar1 + k0);
        gload16(b_d0, Br0 + k0);
        gload16(b_d1, Br1 + k0);
        __syncthreads();

        bf16x8 af[4], bfr[4];
#pragma unroll
        for (int i = 0; i < 4; ++i)
            af[i] = *(const bf16x8*)&a_s[(wm + i * 16 + lr) * BK + kg * 8];
#pragma unroll
        for (int j = 0; j < 4; ++j)
            bfr[j] = *(const bf16x8*)&b_s[(wn + j * 16 + lr) * BK + kg * 8];
#pragma unroll
        for (int i = 0; i < 4; ++i)
#pragma unroll
            for (int j = 0; j < 4; ++j)
                acc[i][j] = __builtin_amdgcn_mfma_f32_16x16x32_bf16(af[i], bfr[j], acc[i][j], 0, 0, 0);
    }

    const int r0 = kg * 4;
#pragma unroll
    for (int i = 0; i < 4; ++i) {
#pragma unroll
        for (int j = 0; j < 4; ++j) {
            const int col = bn + wn + j * 16 + lr;
#pragma unroll
            for (int r = 0; r < 4; ++r) {
                const int row = bm + wm + i * 16 + r0 + r;
                Cb[(size_t)row * 8192 + col] = f2bf(acc[i][j][r]);
            }
        }
    }
}

// ---------------------------------------------------------------------------
// PV: out[q][d] = att[q][:] . value_t[d][:]  (A,Bt bf16, C f32)
// 64x64 tiles, splitK=2 over z (chunk 4096), grid (16,64,2), XCD swizzle.
// z=0 -> out, z=1 -> part.
// ---------------------------------------------------------------------------
__global__ __launch_bounds__(256)
void pv_gemm(const u16* __restrict__ A, const u16* __restrict__ Bt,
             float* __restrict__ C0, float* __restrict__ C1)
{
    __shared__ u16 a_s[64 * BK];
    __shared__ u16 b_s[64 * BK];
    const int lin = blockIdx.x + (blockIdx.y << 4) + (blockIdx.z << 10);
    const int swz = xcd_map(lin, 2048);
    const int bz  = swz >> 10;
    const int bm  = ((swz & 1023) >> 4) * 64;
    const int bn  = (swz & 15) * 64;

    const int tid  = threadIdx.x;
    const int lane = tid & 63;
    const int wid  = tid >> 6;
    const int lr   = lane & 15;
    const int kg   = lane >> 4;
    const int wm   = (wid >> 1) * 32;
    const int wn   = (wid & 1) * 32;
    const int srow = tid >> 2;        // 0..63
    const int scol = (tid & 3) * 8;

    const int kBeg = bz << 12;        // 0 or 4096
    const u16* Ar = A  + (size_t)(bm + srow) * 8192 + kBeg + scol;
    const u16* Br = Bt + (size_t)(bn + srow) * 8192 + kBeg + scol;
    u16* a_d = a_s + wid * 512;
    u16* b_d = b_s + wid * 512;
    float* Cv = bz ? C1 : C0;

    f32x4 acc[2][2];
#pragma unroll
    for (int i = 0; i < 2; ++i)
#pragma unroll
        for (int j = 0; j < 2; ++j)
            acc[i][j] = (f32x4){0.f, 0.f, 0.f, 0.f};

    for (int k0 = 0; k0 < 4096; k0 += BK) {
        __syncthreads();
        gload16(a_d, Ar + k0);
        gload16(b_d, Br + k0);
        __syncthreads();

        bf16x8 af[2], bfr[2];
#pragma unroll
        for (int i = 0; i < 2; ++i)
            af[i] = *(const bf16x8*)&a_s[(wm + i * 16 + lr) * BK + kg * 8];
#pragma unroll
        for (int j = 0; j < 2; ++j)
            bfr[j] = *(const bf16x8*)&b_s[(wn + j * 16 + lr) * BK + kg * 8];
#pragma unroll
        for (int i = 0; i < 2; ++i)
#pragma unroll
            for (int j = 0; j < 2; ++j)
                acc[i][j] = __builtin_amdgcn_mfma_f32_16x16x32_bf16(af[i], bfr[j], acc[i][j], 0, 0, 0);
    }

    const int r0 = kg * 4;
#pragma unroll
    for (int i = 0; i < 2; ++i) {
#pragma unroll
        for (int j = 0; j < 2; ++j) {
            const int col = bn + wn + j * 16 + lr;
#pragma unroll
            for (int r = 0; r < 4; ++r) {
                const int row = bm + wm + i * 16 + r0 + r;
                Cv[(size_t)row * 1024 + col] = acc[i][j][r];
            }
        }
    }
}

// out[c*ldout + r] = bf16(in[r*ldin + c]) for the three 1024x1024 f32 weights.
__global__ __launch_bounds__(256)
void wtrans(const float* __restrict__ Qw, const float* __restrict__ Kw,
            const float* __restrict__ Vw, u16* __restrict__ Qt,
            u16* __restrict__ Kt, u16* __restrict__ Vt)
{
    __shared__ u16 tile[64][65];
    const float* in = (blockIdx.z == 0) ? Qw : (blockIdx.z == 1) ? Kw : Vw;
    u16* out        = (blockIdx.z == 0) ? Qt : (blockIdx.z == 1) ? Kt : Vt;
    const int r0 = blockIdx.y * 64;
    const int c0 = blockIdx.x * 64;
    const int tr = threadIdx.x >> 2;
    const int tq = threadIdx.x & 3;

    const float* p = in + (size_t)(r0 + tr) * 1024 + c0 + tq * 16;
#pragma unroll
    for (int i = 0; i < 16; i += 4) {
        float4 v = *(const float4*)(p + i);
        tile[tq * 16 + i + 0][tr] = f2bf(v.x);
        tile[tq * 16 + i + 1][tr] = f2bf(v.y);
        tile[tq * 16 + i + 2][tr] = f2bf(v.z);
        tile[tq * 16 + i + 3][tr] = f2bf(v.w);
    }
    __syncthreads();

    u16 tmp[16];
#pragma unroll
    for (int i = 0; i < 16; ++i) tmp[i] = tile[tr][tq * 16 + i];
    bf16x8 w0, w1;
#pragma unroll
    for (int j = 0; j < 8; ++j) { w0[j] = (short)tmp[j]; w1[j] = (short)tmp[8 + j]; }
    u16* o = out + (size_t)(c0 + tr) * 1024 + r0 + tq * 16;
    *(bf16x8*)o       = w0;
    *(bf16x8*)(o + 8) = w1;
}

// f32 -> bf16 for host (blocks 0..2047) and guests (2048..6143).
__global__ __launch_bounds__(256)
void cvt_inputs(const float* __restrict__ host, const float* __restrict__ guests,
                u16* __restrict__ host_bf, u16* __restrict__ guests_bf)
{
    int b = blockIdx.x;
    const float* in; u16* out;
    if (b < 2048) { in = host; out = host_bf; }
    else          { in = guests; out = guests_bf; b -= 2048; }
    const size_t i = ((size_t)b * 256 + threadIdx.x) * 8;
    float4 v0 = *(const float4*)(in + i);
    float4 v1 = *(const float4*)(in + i + 4);
    bf16x8 w;
    w[0] = (short)f2bf(v0.x); w[1] = (short)f2bf(v0.y);
    w[2] = (short)f2bf(v0.z); w[3] = (short)f2bf(v0.w);
    w[4] = (short)f2bf(v1.x); w[5] = (short)f2bf(v1.y);
    w[6] = (short)f2bf(v1.z); w[7] = (short)f2bf(v1.w);
    *(bf16x8*)(out + i) = w;
}

// out += p
__global__ __launch_bounds__(256)
void add_f32(float* __restrict__ out, const float* __restrict__ p)
{
    const size_t i = ((size_t)blockIdx.x * 256 + threadIdx.x) * 4;
    float4 a = *(const float4*)(out + i);
    float4 b = *(const float4*)(p + i);
    a.x += b.x; a.y += b.y; a.z += b.z; a.w += b.w;
    *(float4*)(out + i) = a;
}

// In-place row softmax over bf16 logits, one block per row of 8192.
__global__ __launch_bounds__(256)
void softmax_inplace(u16* __restrict__ att)
{
    const int tid = threadIdx.x;
    u16* p = att + (size_t)blockIdx.x * 8192;

    float x[32];
#pragma unroll
    for (int c = 0; c < 4; ++c) {
        bf16x8 v = *(const bf16x8*)(p + c * 2048 + tid * 8);
#pragma unroll
        for (int j = 0; j < 8; ++j) x[c * 8 + j] = bf2f((u16)v[j]);
    }

    float mx = -1e30f;
#pragma unroll
    for (int i = 0; i < 32; ++i) mx = fmaxf(mx, x[i]);
#pragma unroll
    for (int o = 32; o >= 1; o >>= 1) mx = fmaxf(mx, __shfl_xor(mx, o));

    __shared__ float red[8];
    const int wid = tid >> 6, lane = tid & 63;
    if (lane == 0) red[wid] = mx;
    __syncthreads();
    mx = fmaxf(fmaxf(red[0], red[1]), fmaxf(red[2], red[3]));

    float s = 0.f;
#pragma unroll
    for (int i = 0; i < 32; ++i) { x[i] = __expf(x[i] - mx); s += x[i]; }
#pragma unroll
    for (int o = 32; o >= 1; o >>= 1) s += __shfl_xor(s, o);
    if (lane == 0) red[4 + wid] = s;
    __syncthreads();
    s = red[4] + red[5] + red[6] + red[7];
    const float inv = 1.0f / s;

#pragma unroll
    for (int c = 0; c < 4; ++c) {
        bf16x8 w;
#pragma unroll
        for (int j = 0; j < 8; ++j) w[j] = (short)f2bf(x[c * 8 + j] * inv);
        *(bf16x8*)(p + c * 2048 + tid * 8) = w;
    }
}

extern "C" void kernel_launch(void* const* d_in, const int* in_sizes, int n_in,
                              void* d_out, int out_size, void* d_ws, size_t ws_size,
                              hipStream_t stream)
{
    const float* host   = (const float*)d_in[0];  // [4096][1024]
    const float* guests = (const float*)d_in[1];  // [8192][1024]
    const float* Qw     = (const float*)d_in[2];  // [1024][1024]
    const float* Kw     = (const float*)d_in[3];
    const float* Vw     = (const float*)d_in[4];
    float* out = (float*)d_out;                   // [4096][1024]

    char* ws = (char*)d_ws;
    // Lifetime-overlapped layout (peak 104 MB):
    //   [0..64)   att (phases 3-5)  | host_bf@0..8, guests_bf@8..24, W@24..30 (phases 1-2)
    //   [64..72)  query_bf (2-3)    | part (phase 5, 64..80 over dead query/key)
    //   [72..88)  key_bf (2-3)
    //   [88..104) value_t (2-5)
    u16* att       = (u16*)(ws);
    u16* host_bf   = (u16*)(ws);
    u16* guests_bf = (u16*)(ws + ( 8ull << 20));
    u16* Qt        = (u16*)(ws + (24ull << 20));
    u16* Kt        = (u16*)(ws + (26ull << 20));
    u16* Vt        = (u16*)(ws + (28ull << 20));
    u16* query_bf  = (u16*)(ws + (64ull << 20));
    u16* key_bf    = (u16*)(ws + (72ull << 20));
    u16* value_t   = (u16*)(ws + (88ull << 20));
    float* part    = (float*)(ws + (64ull << 20));

    dim3 blk(256);

    // phase 1: dtype prep
    cvt_inputs<<<dim3(6144), blk, 0, stream>>>(host, guests, host_bf, guests_bf);
    wtrans<<<dim3(16, 16, 3), blk, 0, stream>>>(Qw, Kw, Vw, Qt, Kt, Vt);

    // phase 2: all projections (query pre-scaled by 1/32; value written transposed)
    proj_gemm<<<dim3(1280), blk, 0, stream>>>(host_bf, guests_bf, Qt, Kt, Vt,
                                              query_bf, key_bf, value_t);

    // phase 3: att = (q/32) . k
    qkt_gemm<<<dim3(64, 32), blk, 0, stream>>>(query_bf, key_bf, att);

    // phase 4: softmax rows in place
    softmax_inplace<<<dim3(4096), blk, 0, stream>>>(att);

    // phase 5: out = P @ V  (splitK=2: z=0 -> out, z=1 -> part)
    pv_gemm<<<dim3(16, 64, 2), blk, 0, stream>>>(att, value_t, out, part);
    add_f32<<<dim3(4096), blk, 0, stream>>>(out, part);
}

// Round 5
// 384.865 us; speedup vs baseline: 1.4420x; 1.1192x over previous
//
#include <hip/hip_runtime.h>
#include <stdint.h>

typedef float f32x4 __attribute__((ext_vector_type(4)));
typedef short bf16x8 __attribute__((ext_vector_type(8)));
typedef unsigned short u16;
typedef u16 u16x4 __attribute__((ext_vector_type(4)));

__device__ __forceinline__ u16 f2bf(float f) {
    union { float f; uint32_t u; } v; v.f = f;
    uint32_t r = v.u + 0x7FFFu + ((v.u >> 16) & 1u);
    return (u16)(r >> 16);
}
__device__ __forceinline__ float bf2f(u16 b) {
    union { uint32_t u; float f; } v; v.u = ((uint32_t)b) << 16;
    return v.f;
}

// async global->LDS, 16B/lane; LDS dest is wave-uniform base + lane*16.
__device__ __forceinline__ void gload16(u16* lds, const u16* g) {
    __builtin_amdgcn_global_load_lds(
        (const __attribute__((address_space(1))) void*)(uintptr_t)g,
        (__attribute__((address_space(3))) void*)(uint32_t)(uintptr_t)lds,
        16, 0, 0);
}

// XCD-aware chunked remap (bijective when nwg % 8 == 0).
__device__ __forceinline__ int xcd_map(int bid, int nwg) {
    return (bid & 7) * (nwg >> 3) + (bid >> 3);
}

#define BK 32

// ---------------------------------------------------------------------------
// Merged projection GEMM: 128x128 tiles, K=1024, all-bf16.
//   group 0: query = host_bf @ Qt -> query_bf row-major, *1/32
//   group 1: key   = guests @ Kt  -> key_bf row-major
//   group 2: value = guests @ Vt  -> value_t TRANSPOSED [d][m]
// ---------------------------------------------------------------------------
__global__ __launch_bounds__(256)
void proj_gemm(const u16* __restrict__ host_bf, const u16* __restrict__ guests_bf,
               const u16* __restrict__ Qt, const u16* __restrict__ Kt,
               const u16* __restrict__ Vt,
               u16* __restrict__ query_bf, u16* __restrict__ key_bf,
               u16* __restrict__ value_t)
{
    __shared__ u16 a_s[128 * BK];
    __shared__ u16 b_s[128 * BK];
    const int id = xcd_map(blockIdx.x, 1280);

    const u16 *A, *B; u16* Crm = nullptr; int bm, bn; int group;
    if (id < 256)      { group = 0; A = host_bf;   B = Qt; Crm = query_bf; bm = (id >> 3) * 128;         bn = (id & 7) * 128; }
    else if (id < 768) { group = 1; A = guests_bf; B = Kt; Crm = key_bf;   bm = ((id - 256) >> 3) * 128; bn = ((id - 256) & 7) * 128; }
    else               { group = 2; A = guests_bf; B = Vt; Crm = nullptr;  bm = ((id - 768) >> 3) * 128; bn = ((id - 768) & 7) * 128; }

    const int tid  = threadIdx.x;
    const int lane = tid & 63;
    const int wid  = tid >> 6;
    const int lr   = lane & 15;
    const int kg   = lane >> 4;
    const int wm   = (wid >> 1) * 64;
    const int wn   = (wid & 1) * 64;
    const int srow = tid >> 2;
    const int scol = (tid & 3) * 8;

    const u16* Ar0 = A + (size_t)(bm + srow) * 1024 + scol;
    const u16* Ar1 = A + (size_t)(bm + 64 + srow) * 1024 + scol;
    const u16* Br0 = B + (size_t)(bn + srow) * 1024 + scol;
    const u16* Br1 = B + (size_t)(bn + 64 + srow) * 1024 + scol;
    u16* a_d0 = a_s + wid * 512;
    u16* a_d1 = a_s + 2048 + wid * 512;
    u16* b_d0 = b_s + wid * 512;
    u16* b_d1 = b_s + 2048 + wid * 512;

    f32x4 acc[4][4];
#pragma unroll
    for (int i = 0; i < 4; ++i)
#pragma unroll
        for (int j = 0; j < 4; ++j)
            acc[i][j] = (f32x4){0.f, 0.f, 0.f, 0.f};

    for (int k0 = 0; k0 < 1024; k0 += BK) {
        __syncthreads();
        gload16(a_d0, Ar0 + k0);
        gload16(a_d1, Ar1 + k0);
        gload16(b_d0, Br0 + k0);
        gload16(b_d1, Br1 + k0);
        __syncthreads();

        bf16x8 af[4], bfr[4];
#pragma unroll
        for (int i = 0; i < 4; ++i)
            af[i] = *(const bf16x8*)&a_s[(wm + i * 16 + lr) * BK + kg * 8];
#pragma unroll
        for (int j = 0; j < 4; ++j)
            bfr[j] = *(const bf16x8*)&b_s[(wn + j * 16 + lr) * BK + kg * 8];
#pragma unroll
        for (int i = 0; i < 4; ++i)
#pragma unroll
            for (int j = 0; j < 4; ++j)
                acc[i][j] = __builtin_amdgcn_mfma_f32_16x16x32_bf16(af[i], bfr[j], acc[i][j], 0, 0, 0);
    }

    const int r0 = kg * 4;
    if (group == 2) {
#pragma unroll
        for (int i = 0; i < 4; ++i) {
#pragma unroll
            for (int j = 0; j < 4; ++j) {
                const int col = bn + wn + j * 16 + lr;
                const int row = bm + wm + i * 16 + r0;
                u16x4 w;
#pragma unroll
                for (int r = 0; r < 4; ++r) w[r] = f2bf(acc[i][j][r]);
                *(u16x4*)&value_t[(size_t)col * 8192 + row] = w;
            }
        }
    } else {
        const float scale = (group == 0) ? 0.03125f : 1.0f;
#pragma unroll
        for (int i = 0; i < 4; ++i) {
#pragma unroll
            for (int j = 0; j < 4; ++j) {
                const int col = bn + wn + j * 16 + lr;
#pragma unroll
                for (int r = 0; r < 4; ++r) {
                    const int row = bm + wm + i * 16 + r0 + r;
                    Crm[(size_t)row * 1024 + col] = f2bf(acc[i][j][r] * scale);
                }
            }
        }
    }
}

// ---------------------------------------------------------------------------
// QK^T: att[q][m] = query_bf[q][:] . key_bf[m][:]; 128x128 tiles, C bf16.
// ---------------------------------------------------------------------------
__global__ __launch_bounds__(256)
void qkt_gemm(const u16* __restrict__ A, const u16* __restrict__ Bt,
              u16* __restrict__ Cb)
{
    __shared__ u16 a_s[128 * BK];
    __shared__ u16 b_s[128 * BK];
    const int lin = blockIdx.x + (blockIdx.y << 6);
    const int swz = xcd_map(lin, 2048);
    const int bm = (swz >> 6) * 128;
    const int bn = (swz & 63) * 128;

    const int tid  = threadIdx.x;
    const int lane = tid & 63;
    const int wid  = tid >> 6;
    const int lr   = lane & 15;
    const int kg   = lane >> 4;
    const int wm   = (wid >> 1) * 64;
    const int wn   = (wid & 1) * 64;
    const int srow = tid >> 2;
    const int scol = (tid & 3) * 8;

    const u16* Ar0 = A  + (size_t)(bm + srow) * 1024 + scol;
    const u16* Ar1 = A  + (size_t)(bm + 64 + srow) * 1024 + scol;
    const u16* Br0 = Bt + (size_t)(bn + srow) * 1024 + scol;
    const u16* Br1 = Bt + (size_t)(bn + 64 + srow) * 1024 + scol;
    u16* a_d0 = a_s + wid * 512;
    u16* a_d1 = a_s + 2048 + wid * 512;
    u16* b_d0 = b_s + wid * 512;
    u16* b_d1 = b_s + 2048 + wid * 512;

    f32x4 acc[4][4];
#pragma unroll
    for (int i = 0; i < 4; ++i)
#pragma unroll
        for (int j = 0; j < 4; ++j)
            acc[i][j] = (f32x4){0.f, 0.f, 0.f, 0.f};

    for (int k0 = 0; k0 < 1024; k0 += BK) {
        __syncthreads();
        gload16(a_d0, Ar0 + k0);
        gload16(a_d1, Ar1 + k0);
        gload16(b_d0, Br0 + k0);
        gload16(b_d1, Br1 + k0);
        __syncthreads();

        bf16x8 af[4], bfr[4];
#pragma unroll
        for (int i = 0; i < 4; ++i)
            af[i] = *(const bf16x8*)&a_s[(wm + i * 16 + lr) * BK + kg * 8];
#pragma unroll
        for (int j = 0; j < 4; ++j)
            bfr[j] = *(const bf16x8*)&b_s[(wn + j * 16 + lr) * BK + kg * 8];
#pragma unroll
        for (int i = 0; i < 4; ++i)
#pragma unroll
            for (int j = 0; j < 4; ++j)
                acc[i][j] = __builtin_amdgcn_mfma_f32_16x16x32_bf16(af[i], bfr[j], acc[i][j], 0, 0, 0);
    }

    const int r0 = kg * 4;
#pragma unroll
    for (int i = 0; i < 4; ++i) {
#pragma unroll
        for (int j = 0; j < 4; ++j) {
            const int col = bn + wn + j * 16 + lr;
#pragma unroll
            for (int r = 0; r < 4; ++r) {
                const int row = bm + wm + i * 16 + r0 + r;
                Cb[(size_t)row * 8192 + col] = f2bf(acc[i][j][r]);
            }
        }
    }
}

// ---------------------------------------------------------------------------
// PV: out[q][d] = att[q][:] . value_t[d][:]  (A,Bt bf16, C f32)
// 128x128 tiles, splitK=3 (chunks 2752/2752/2688), grid 768, XCD swizzle.
// z=0 -> C0(out), z=1 -> C1, z=2 -> C2.
// ---------------------------------------------------------------------------
__global__ __launch_bounds__(256)
void pv_gemm(const u16* __restrict__ A, const u16* __restrict__ Bt,
             float* __restrict__ C0, float* __restrict__ C1, float* __restrict__ C2)
{
    __shared__ u16 a_s[128 * BK];
    __shared__ u16 b_s[128 * BK];
    const int swz = xcd_map(blockIdx.x, 768);
    const int z   = swz >> 8;          // 0..2
    const int rem = swz & 255;
    const int bm  = (rem >> 3) * 128;  // 32 row tiles
    const int bn  = (rem & 7) * 128;   // 8 col tiles

    const int tid  = threadIdx.x;
    const int lane = tid & 63;
    const int wid  = tid >> 6;
    const int lr   = lane & 15;
    const int kg   = lane >> 4;
    const int wm   = (wid >> 1) * 64;
    const int wn   = (wid & 1) * 64;
    const int srow = tid >> 2;
    const int scol = (tid & 3) * 8;

    const int kBeg = z * 2752;
    const int kEnd = (z == 2) ? 8192 : kBeg + 2752;
    float* Cv = (z == 0) ? C0 : (z == 1) ? C1 : C2;

    const u16* Ar0 = A  + (size_t)(bm + srow) * 8192 + scol;
    const u16* Ar1 = A  + (size_t)(bm + 64 + srow) * 8192 + scol;
    const u16* Br0 = Bt + (size_t)(bn + srow) * 8192 + scol;
    const u16* Br1 = Bt + (size_t)(bn + 64 + srow) * 8192 + scol;
    u16* a_d0 = a_s + wid * 512;
    u16* a_d1 = a_s + 2048 + wid * 512;
    u16* b_d0 = b_s + wid * 512;
    u16* b_d1 = b_s + 2048 + wid * 512;

    f32x4 acc[4][4];
#pragma unroll
    for (int i = 0; i < 4; ++i)
#pragma unroll
        for (int j = 0; j < 4; ++j)
            acc[i][j] = (f32x4){0.f, 0.f, 0.f, 0.f};

    for (int k0 = kBeg; k0 < kEnd; k0 += BK) {
        __syncthreads();
        gload16(a_d0, Ar0 + k0);
        gload16(a_d1, Ar1 + k0);
        gload16(b_d0, Br0 + k0);
        gload16(b_d1, Br1 + k0);
        __syncthreads();

        bf16x8 af[4], bfr[4];
#pragma unroll
        for (int i = 0; i < 4; ++i)
            af[i] = *(const bf16x8*)&a_s[(wm + i * 16 + lr) * BK + kg * 8];
#pragma unroll
        for (int j = 0; j < 4; ++j)
            bfr[j] = *(const bf16x8*)&b_s[(wn + j * 16 + lr) * BK + kg * 8];
#pragma unroll
        for (int i = 0; i < 4; ++i)
#pragma unroll
            for (int j = 0; j < 4; ++j)
                acc[i][j] = __builtin_amdgcn_mfma_f32_16x16x32_bf16(af[i], bfr[j], acc[i][j], 0, 0, 0);
    }

    const int r0 = kg * 4;
#pragma unroll
    for (int i = 0; i < 4; ++i) {
#pragma unroll
        for (int j = 0; j < 4; ++j) {
            const int col = bn + wn + j * 16 + lr;
#pragma unroll
            for (int r = 0; r < 4; ++r) {
                const int row = bm + wm + i * 16 + r0 + r;
                Cv[(size_t)row * 1024 + col] = acc[i][j][r];
            }
        }
    }
}

// out[c*1024 + r] = bf16(in[r*1024 + c]) for the three 1024x1024 f32 weights.
__global__ __launch_bounds__(256)
void wtrans(const float* __restrict__ Qw, const float* __restrict__ Kw,
            const float* __restrict__ Vw, u16* __restrict__ Qt,
            u16* __restrict__ Kt, u16* __restrict__ Vt)
{
    __shared__ u16 tile[64][65];
    const float* in = (blockIdx.z == 0) ? Qw : (blockIdx.z == 1) ? Kw : Vw;
    u16* out        = (blockIdx.z == 0) ? Qt : (blockIdx.z == 1) ? Kt : Vt;
    const int r0 = blockIdx.y * 64;
    const int c0 = blockIdx.x * 64;
    const int tr = threadIdx.x >> 2;
    const int tq = threadIdx.x & 3;

    const float* p = in + (size_t)(r0 + tr) * 1024 + c0 + tq * 16;
#pragma unroll
    for (int i = 0; i < 16; i += 4) {
        float4 v = *(const float4*)(p + i);
        tile[tq * 16 + i + 0][tr] = f2bf(v.x);
        tile[tq * 16 + i + 1][tr] = f2bf(v.y);
        tile[tq * 16 + i + 2][tr] = f2bf(v.z);
        tile[tq * 16 + i + 3][tr] = f2bf(v.w);
    }
    __syncthreads();

    u16 tmp[16];
#pragma unroll
    for (int i = 0; i < 16; ++i) tmp[i] = tile[tr][tq * 16 + i];
    bf16x8 w0, w1;
#pragma unroll
    for (int j = 0; j < 8; ++j) { w0[j] = (short)tmp[j]; w1[j] = (short)tmp[8 + j]; }
    u16* o = out + (size_t)(c0 + tr) * 1024 + r0 + tq * 16;
    *(bf16x8*)o       = w0;
    *(bf16x8*)(o + 8) = w1;
}

// f32 -> bf16 for host (blocks 0..2047) and guests (2048..6143).
__global__ __launch_bounds__(256)
void cvt_inputs(const float* __restrict__ host, const float* __restrict__ guests,
                u16* __restrict__ host_bf, u16* __restrict__ guests_bf)
{
    int b = blockIdx.x;
    const float* in; u16* out;
    if (b < 2048) { in = host; out = host_bf; }
    else          { in = guests; out = guests_bf; b -= 2048; }
    const size_t i = ((size_t)b * 256 + threadIdx.x) * 8;
    float4 v0 = *(const float4*)(in + i);
    float4 v1 = *(const float4*)(in + i + 4);
    bf16x8 w;
    w[0] = (short)f2bf(v0.x); w[1] = (short)f2bf(v0.y);
    w[2] = (short)f2bf(v0.z); w[3] = (short)f2bf(v0.w);
    w[4] = (short)f2bf(v1.x); w[5] = (short)f2bf(v1.y);
    w[6] = (short)f2bf(v1.z); w[7] = (short)f2bf(v1.w);
    *(bf16x8*)(out + i) = w;
}

// out += p1 + p2
__global__ __launch_bounds__(256)
void add2_f32(float* __restrict__ out, const float* __restrict__ p1,
              const float* __restrict__ p2)
{
    const size_t i = ((size_t)blockIdx.x * 256 + threadIdx.x) * 4;
    float4 a = *(const float4*)(out + i);
    float4 b = *(const float4*)(p1 + i);
    float4 c = *(const float4*)(p2 + i);
    a.x += b.x + c.x; a.y += b.y + c.y; a.z += b.z + c.z; a.w += b.w + c.w;
    *(float4*)(out + i) = a;
}

// In-place row softmax over bf16 logits, one block per row of 8192.
__global__ __launch_bounds__(256)
void softmax_inplace(u16* __restrict__ att)
{
    const int tid = threadIdx.x;
    u16* p = att + (size_t)blockIdx.x * 8192;

    float x[32];
#pragma unroll
    for (int c = 0; c < 4; ++c) {
        bf16x8 v = *(const bf16x8*)(p + c * 2048 + tid * 8);
#pragma unroll
        for (int j = 0; j < 8; ++j) x[c * 8 + j] = bf2f((u16)v[j]);
    }

    float mx = -1e30f;
#pragma unroll
    for (int i = 0; i < 32; ++i) mx = fmaxf(mx, x[i]);
#pragma unroll
    for (int o = 32; o >= 1; o >>= 1) mx = fmaxf(mx, __shfl_xor(mx, o));

    __shared__ float red[8];
    const int wid = tid >> 6, lane = tid & 63;
    if (lane == 0) red[wid] = mx;
    __syncthreads();
    mx = fmaxf(fmaxf(red[0], red[1]), fmaxf(red[2], red[3]));

    float s = 0.f;
#pragma unroll
    for (int i = 0; i < 32; ++i) { x[i] = __expf(x[i] - mx); s += x[i]; }
#pragma unroll
    for (int o = 32; o >= 1; o >>= 1) s += __shfl_xor(s, o);
    if (lane == 0) red[4 + wid] = s;
    __syncthreads();
    s = red[4] + red[5] + red[6] + red[7];
    const float inv = 1.0f / s;

#pragma unroll
    for (int c = 0; c < 4; ++c) {
        bf16x8 w;
#pragma unroll
        for (int j = 0; j < 8; ++j) w[j] = (short)f2bf(x[c * 8 + j] * inv);
        *(bf16x8*)(p + c * 2048 + tid * 8) = w;
    }
}

extern "C" void kernel_launch(void* const* d_in, const int* in_sizes, int n_in,
                              void* d_out, int out_size, void* d_ws, size_t ws_size,
                              hipStream_t stream)
{
    const float* host   = (const float*)d_in[0];  // [4096][1024]
    const float* guests = (const float*)d_in[1];  // [8192][1024]
    const float* Qw     = (const float*)d_in[2];  // [1024][1024]
    const float* Kw     = (const float*)d_in[3];
    const float* Vw     = (const float*)d_in[4];
    float* out = (float*)d_out;                   // [4096][1024]

    char* ws = (char*)d_ws;
    // Lifetime-overlapped layout (peak 120 MB):
    //   [0..64)    att (ph 3-5)   | host_bf@0..8, guests_bf@8..24, W@24..30 (ph 1-2)
    //   [64..72)   query_bf (2-3) | part1 @ [64..80) (ph 5, over dead query/key)
    //   [72..88)   key_bf (2-3)
    //   [88..104)  value_t (2-5)
    //   [104..120) part2 (ph 5)
    u16* att       = (u16*)(ws);
    u16* host_bf   = (u16*)(ws);
    u16* guests_bf = (u16*)(ws + ( 8ull << 20));
    u16* Qt        = (u16*)(ws + (24ull << 20));
    u16* Kt        = (u16*)(ws + (26ull << 20));
    u16* Vt        = (u16*)(ws + (28ull << 20));
    u16* query_bf  = (u16*)(ws + (64ull << 20));
    u16* key_bf    = (u16*)(ws + (72ull << 20));
    u16* value_t   = (u16*)(ws + (88ull << 20));
    float* part1   = (float*)(ws + (64ull << 20));
    float* part2   = (float*)(ws + (104ull << 20));

    dim3 blk(256);

    // phase 1: dtype prep
    cvt_inputs<<<dim3(6144), blk, 0, stream>>>(host, guests, host_bf, guests_bf);
    wtrans<<<dim3(16, 16, 3), blk, 0, stream>>>(Qw, Kw, Vw, Qt, Kt, Vt);

    // phase 2: all projections (query pre-scaled by 1/32; value written transposed)
    proj_gemm<<<dim3(1280), blk, 0, stream>>>(host_bf, guests_bf, Qt, Kt, Vt,
                                              query_bf, key_bf, value_t);

    // phase 3: att = (q/32) . k
    qkt_gemm<<<dim3(64, 32), blk, 0, stream>>>(query_bf, key_bf, att);

    // phase 4: softmax rows in place
    softmax_inplace<<<dim3(4096), blk, 0, stream>>>(att);

    // phase 5: out = P @ V  (128^2 tiles, splitK=3)
    pv_gemm<<<dim3(768), blk, 0, stream>>>(att, value_t, out, part1, part2);
    add2_f32<<<dim3(4096), blk, 0, stream>>>(out, part1, part2);
}

// Round 6
// 350.092 us; speedup vs baseline: 1.5852x; 1.0993x over previous
//
#include <hip/hip_runtime.h>
#include <stdint.h>

typedef float f32x4 __attribute__((ext_vector_type(4)));
typedef short bf16x8 __attribute__((ext_vector_type(8)));
typedef unsigned short u16;
typedef u16 u16x4 __attribute__((ext_vector_type(4)));

__device__ __forceinline__ u16 f2bf(float f) {
    union { float f; uint32_t u; } v; v.f = f;
    uint32_t r = v.u + 0x7FFFu + ((v.u >> 16) & 1u);
    return (u16)(r >> 16);
}
__device__ __forceinline__ float bf2f(u16 b) {
    union { uint32_t u; float f; } v; v.u = ((uint32_t)b) << 16;
    return v.f;
}

// async global->LDS, 16B/lane; LDS dest is wave-uniform base + lane*16.
__device__ __forceinline__ void gload16(u16* lds, const u16* g) {
    __builtin_amdgcn_global_load_lds(
        (const __attribute__((address_space(1))) void*)(uintptr_t)g,
        (__attribute__((address_space(3))) void*)(uint32_t)(uintptr_t)lds,
        16, 0, 0);
}

// XCD-aware chunked remap (bijective when nwg % 8 == 0).
__device__ __forceinline__ int xcd_map(int bid, int nwg) {
    return (bid & 7) * (nwg >> 3) + (bid >> 3);
}

#define BK 32

// ===========================================================================
// 256x256 8-phase GEMM core (plain-HIP port of the HK/m201 schedule).
// C[M][N] = A[M][K] @ Bt[N][K]^T, bf16 in, f32 acc.
// 512 threads = 8 waves (2 M x 4 N); per-wave out 128x64; BK=64 per K-tile.
// LDS 128 KiB: 2 buffers x (A 256x64 + B 256x64), each tile as 2 halves of
// 128x64. Staging via global_load_lds with PRE-SWIZZLED global source
// (colu16 ^= (row&7)*8); ds_read applies the same XOR -> conflict-free.
// Per K-tile 4 phases; staging 1.5 tiles ahead; vmcnt(4) once per tile.
// ===========================================================================
__device__ __forceinline__ void gemm256_core(
    const u16* __restrict__ A, const u16* __restrict__ Bt,
    int lda, int ldb, int bm, int bn, int kBeg, int nt,
    u16* lds, f32x4 (&acc)[8][4])
{
    const int tid  = threadIdx.x;
    const int lane = tid & 63;
    const int wid  = tid >> 6;
    const int lr   = lane & 15;
    const int kg   = lane >> 4;
    const int wr   = wid >> 2;   // 0..1
    const int wc   = wid & 3;    // 0..3

    // staging: thread -> phys (row = tid>>3 within 64-row call, col = (tid&7)*8);
    // source col pre-swizzled so linear LDS write lands data in swizzled slot.
    const int sr = tid >> 3;                         // 0..63
    const int sc = ((tid & 7) ^ (sr & 7)) * 8;       // swizzled source col (u16)
    const u16* As = A  + (size_t)(bm + sr) * lda + kBeg + sc;
    const u16* Bs = Bt + (size_t)(bn + sr) * ldb + kBeg + sc;
    const int ldsW = wid * 512;                      // wave-uniform LDS base (u16)

    // fragment read offsets (u16 units, within one 32768-u16 buffer)
    int arow[8], brow[4], kc[2];
#pragma unroll
    for (int m = 0; m < 8; ++m) arow[m] = wr * 8192 + (m * 16 + lr) * 64;
#pragma unroll
    for (int n = 0; n < 4; ++n)
        brow[n] = 16384 + (wc >> 1) * 8192 + ((wc & 1) * 64 + n * 16 + lr) * 64;
#pragma unroll
    for (int ks = 0; ks < 2; ++ks) kc[ks] = (ks * 32 + kg * 8) ^ ((lr & 7) * 8);

#define STG_A(q, h, t) do { \
        const u16* _s = As + (size_t)((h) * 128) * lda + (t) * 64; \
        gload16(lds + (q) * 32768 + (h) * 8192 + ldsW, _s); \
        gload16(lds + (q) * 32768 + (h) * 8192 + 4096 + ldsW, _s + (size_t)64 * lda); \
    } while (0)
#define STG_B(q, h, t) do { \
        const u16* _s = Bs + (size_t)((h) * 128) * ldb + (t) * 64; \
        gload16(lds + (q) * 32768 + 16384 + (h) * 8192 + ldsW, _s); \
        gload16(lds + (q) * 32768 + 16384 + (h) * 8192 + 4096 + ldsW, _s + (size_t)64 * ldb); \
    } while (0)

    // prologue: tile0 complete into buf0; tile1 B-halves in flight into buf1.
    STG_A(0, 0, 0); STG_A(0, 1, 0); STG_B(0, 0, 0); STG_B(0, 1, 0);
    STG_B(1, 0, 1); STG_B(1, 1, 1);
    asm volatile("s_waitcnt vmcnt(4)" ::: "memory");   // tile0 landed
    __builtin_amdgcn_s_barrier();

    bf16x8 fa[4][2], fb[4][2];
    for (int t = 0; t < nt; ++t) {
        const int p  = t & 1;
        const int pb = p * 32768;

        // -- phase 1: quadrant (m0-3, n0-1); read a0-3 + b0-1; stage Ah0(t+1)
#pragma unroll
        for (int m = 0; m < 4; ++m)
#pragma unroll
            for (int ks = 0; ks < 2; ++ks)
                fa[m][ks] = *(const bf16x8*)&lds[pb + arow[m] + kc[ks]];
#pragma unroll
        for (int n = 0; n < 2; ++n)
#pragma unroll
            for (int ks = 0; ks < 2; ++ks)
                fb[n][ks] = *(const bf16x8*)&lds[pb + brow[n] + kc[ks]];
        if (t + 1 < nt) STG_A(p ^ 1, 0, t + 1);
        __builtin_amdgcn_s_barrier();
        asm volatile("s_waitcnt lgkmcnt(0)" ::: "memory");
        __builtin_amdgcn_sched_barrier(0);
        __builtin_amdgcn_s_setprio(1);
#pragma unroll
        for (int ks = 0; ks < 2; ++ks)
#pragma unroll
            for (int m = 0; m < 4; ++m)
#pragma unroll
                for (int n = 0; n < 2; ++n)
                    acc[m][n] = __builtin_amdgcn_mfma_f32_16x16x32_bf16(fa[m][ks], fb[n][ks], acc[m][n], 0, 0, 0);
        __builtin_amdgcn_s_setprio(0);
        __builtin_amdgcn_s_barrier();

        // -- phase 2: quadrant (m0-3, n2-3); read b2-3; stage Ah1(t+1)
#pragma unroll
        for (int n = 2; n < 4; ++n)
#pragma unroll
            for (int ks = 0; ks < 2; ++ks)
                fb[n][ks] = *(const bf16x8*)&lds[pb + brow[n] + kc[ks]];
        if (t + 1 < nt) STG_A(p ^ 1, 1, t + 1);
        __builtin_amdgcn_s_barrier();
        asm volatile("s_waitcnt lgkmcnt(0)" ::: "memory");
        __builtin_amdgcn_sched_barrier(0);
        __builtin_amdgcn_s_setprio(1);
#pragma unroll
        for (int ks = 0; ks < 2; ++ks)
#pragma unroll
            for (int m = 0; m < 4; ++m)
#pragma unroll
                for (int n = 2; n < 4; ++n)
                    acc[m][n] = __builtin_amdgcn_mfma_f32_16x16x32_bf16(fa[m][ks], fb[n][ks], acc[m][n], 0, 0, 0);
        __builtin_amdgcn_s_setprio(0);
        __builtin_amdgcn_s_barrier();

        // -- phase 3: quadrant (m4-7, n0-1); read a4-7 (reuse fa); stage Bh0(t+2)
#pragma unroll
        for (int m = 0; m < 4; ++m)
#pragma unroll
            for (int ks = 0; ks < 2; ++ks)
                fa[m][ks] = *(const bf16x8*)&lds[pb + arow[4 + m] + kc[ks]];
        if (t + 2 < nt) STG_B(p, 0, t + 2);
        __builtin_amdgcn_s_barrier();
        asm volatile("s_waitcnt lgkmcnt(0)" ::: "memory");
        __builtin_amdgcn_sched_barrier(0);
        __builtin_amdgcn_s_setprio(1);
#pragma unroll
        for (int ks = 0; ks < 2; ++ks)
#pragma unroll
            for (int m = 0; m < 4; ++m)
#pragma unroll
                for (int n = 0; n < 2; ++n)
                    acc[4 + m][n] = __builtin_amdgcn_mfma_f32_16x16x32_bf16(fa[m][ks], fb[n][ks], acc[4 + m][n], 0, 0, 0);
        __builtin_amdgcn_s_setprio(0);
        __builtin_amdgcn_s_barrier();

        // -- phase 4: quadrant (m4-7, n2-3); stage Bh1(t+2); counted vmcnt
        if (t + 2 < nt) STG_B(p, 1, t + 2);
        __builtin_amdgcn_s_barrier();
        __builtin_amdgcn_s_setprio(1);
#pragma unroll
        for (int ks = 0; ks < 2; ++ks)
#pragma unroll
            for (int m = 0; m < 4; ++m)
#pragma unroll
                for (int n = 2; n < 4; ++n)
                    acc[4 + m][n] = __builtin_amdgcn_mfma_f32_16x16x32_bf16(fa[m][ks], fb[n][ks], acc[4 + m][n], 0, 0, 0);
        __builtin_amdgcn_s_setprio(0);
        if (t + 2 < nt)      asm volatile("s_waitcnt vmcnt(4)" ::: "memory"); // tile t+1 landed; Bh(t+2) in flight
        else if (t + 1 < nt) asm volatile("s_waitcnt vmcnt(0)" ::: "memory"); // tail drain
        __builtin_amdgcn_s_barrier();
    }
#undef STG_A
#undef STG_B
}

// QK^T: att[q][m] = query . key, 256^2 tiles, C bf16 (scale folded into query).
__global__ __launch_bounds__(512, 2)
void qkt256(const u16* __restrict__ A, const u16* __restrict__ Bt,
            u16* __restrict__ C)
{
    __shared__ u16 lds[65536];
    const int swz = xcd_map(blockIdx.x, 512);
    const int bm = (swz >> 5) * 256;   // 16 m-tiles
    const int bn = (swz & 31) * 256;   // 32 n-tiles
    f32x4 acc[8][4];
#pragma unroll
    for (int m = 0; m < 8; ++m)
#pragma unroll
        for (int n = 0; n < 4; ++n) acc[m][n] = (f32x4){0.f, 0.f, 0.f, 0.f};
    gemm256_core(A, Bt, 1024, 1024, bm, bn, 0, 16, lds, acc);

    const int lane = threadIdx.x & 63, wid = threadIdx.x >> 6;
    const int lr = lane & 15, kg = lane >> 4, wr = wid >> 2, wc = wid & 3;
#pragma unroll
    for (int m = 0; m < 8; ++m)
#pragma unroll
        for (int n = 0; n < 4; ++n) {
            const int col = bn + wc * 64 + n * 16 + lr;
#pragma unroll
            for (int r = 0; r < 4; ++r) {
                const int row = bm + wr * 128 + m * 16 + kg * 4 + r;
                C[(size_t)row * 8192 + col] = f2bf(acc[m][n][r]);
            }
        }
}

// PV: out[q][d] = att . value_t^T, 256^2 tiles, splitK=3 (43/43/42 K-tiles).
__global__ __launch_bounds__(512, 2)
void pv256(const u16* __restrict__ A, const u16* __restrict__ Bt,
           float* __restrict__ C0, float* __restrict__ C1, float* __restrict__ C2)
{
    __shared__ u16 lds[65536];
    const int swz = xcd_map(blockIdx.x, 192);
    const int z   = swz >> 6;          // 0..2
    const int rem = swz & 63;
    const int bm  = (rem >> 2) * 256;  // 16 m-tiles
    const int bn  = (rem & 3) * 256;   // 4 n-tiles
    const int kBeg = z * 2752;
    const int nt   = (z == 2) ? 42 : 43;
    float* Cv = (z == 0) ? C0 : (z == 1) ? C1 : C2;

    f32x4 acc[8][4];
#pragma unroll
    for (int m = 0; m < 8; ++m)
#pragma unroll
        for (int n = 0; n < 4; ++n) acc[m][n] = (f32x4){0.f, 0.f, 0.f, 0.f};
    gemm256_core(A, Bt, 8192, 8192, bm, bn, kBeg, nt, lds, acc);

    const int lane = threadIdx.x & 63, wid = threadIdx.x >> 6;
    const int lr = lane & 15, kg = lane >> 4, wr = wid >> 2, wc = wid & 3;
#pragma unroll
    for (int m = 0; m < 8; ++m)
#pragma unroll
        for (int n = 0; n < 4; ++n) {
            const int col = bn + wc * 64 + n * 16 + lr;
#pragma unroll
            for (int r = 0; r < 4; ++r) {
                const int row = bm + wr * 128 + m * 16 + kg * 4 + r;
                Cv[(size_t)row * 1024 + col] = acc[m][n][r];
            }
        }
}

// ---------------------------------------------------------------------------
// Merged projection GEMM (unchanged, 128^2 m97-structure): query(*1/32), key,
// value (written transposed).
// ---------------------------------------------------------------------------
__global__ __launch_bounds__(256)
void proj_gemm(const u16* __restrict__ host_bf, const u16* __restrict__ guests_bf,
               const u16* __restrict__ Qt, const u16* __restrict__ Kt,
               const u16* __restrict__ Vt,
               u16* __restrict__ query_bf, u16* __restrict__ key_bf,
               u16* __restrict__ value_t)
{
    __shared__ u16 a_s[128 * BK];
    __shared__ u16 b_s[128 * BK];
    const int id = xcd_map(blockIdx.x, 1280);

    const u16 *A, *B; u16* Crm = nullptr; int bm, bn; int group;
    if (id < 256)      { group = 0; A = host_bf;   B = Qt; Crm = query_bf; bm = (id >> 3) * 128;         bn = (id & 7) * 128; }
    else if (id < 768) { group = 1; A = guests_bf; B = Kt; Crm = key_bf;   bm = ((id - 256) >> 3) * 128; bn = ((id - 256) & 7) * 128; }
    else               { group = 2; A = guests_bf; B = Vt; Crm = nullptr;  bm = ((id - 768) >> 3) * 128; bn = ((id - 768) & 7) * 128; }

    const int tid  = threadIdx.x;
    const int lane = tid & 63;
    const int wid  = tid >> 6;
    const int lr   = lane & 15;
    const int kg   = lane >> 4;
    const int wm   = (wid >> 1) * 64;
    const int wn   = (wid & 1) * 64;
    const int srow = tid >> 2;
    const int scol = (tid & 3) * 8;

    const u16* Ar0 = A + (size_t)(bm + srow) * 1024 + scol;
    const u16* Ar1 = A + (size_t)(bm + 64 + srow) * 1024 + scol;
    const u16* Br0 = B + (size_t)(bn + srow) * 1024 + scol;
    const u16* Br1 = B + (size_t)(bn + 64 + srow) * 1024 + scol;
    u16* a_d0 = a_s + wid * 512;
    u16* a_d1 = a_s + 2048 + wid * 512;
    u16* b_d0 = b_s + wid * 512;
    u16* b_d1 = b_s + 2048 + wid * 512;

    f32x4 acc[4][4];
#pragma unroll
    for (int i = 0; i < 4; ++i)
#pragma unroll
        for (int j = 0; j < 4; ++j)
            acc[i][j] = (f32x4){0.f, 0.f, 0.f, 0.f};

    for (int k0 = 0; k0 < 1024; k0 += BK) {
        __syncthreads();
        gload16(a_d0, Ar0 + k0);
        gload16(a_d1, Ar1 + k0);
        gload16(b_d0, Br0 + k0);
        gload16(b_d1, Br1 + k0);
        __syncthreads();

        bf16x8 af[4], bfr[4];
#pragma unroll
        for (int i = 0; i < 4; ++i)
            af[i] = *(const bf16x8*)&a_s[(wm + i * 16 + lr) * BK + kg * 8];
#pragma unroll
        for (int j = 0; j < 4; ++j)
            bfr[j] = *(const bf16x8*)&b_s[(wn + j * 16 + lr) * BK + kg * 8];
#pragma unroll
        for (int i = 0; i < 4; ++i)
#pragma unroll
            for (int j = 0; j < 4; ++j)
                acc[i][j] = __builtin_amdgcn_mfma_f32_16x16x32_bf16(af[i], bfr[j], acc[i][j], 0, 0, 0);
    }

    const int r0 = kg * 4;
    if (group == 2) {
#pragma unroll
        for (int i = 0; i < 4; ++i) {
#pragma unroll
            for (int j = 0; j < 4; ++j) {
                const int col = bn + wn + j * 16 + lr;
                const int row = bm + wm + i * 16 + r0;
                u16x4 w;
#pragma unroll
                for (int r = 0; r < 4; ++r) w[r] = f2bf(acc[i][j][r]);
                *(u16x4*)&value_t[(size_t)col * 8192 + row] = w;
            }
        }
    } else {
        const float scale = (group == 0) ? 0.03125f : 1.0f;
#pragma unroll
        for (int i = 0; i < 4; ++i) {
#pragma unroll
            for (int j = 0; j < 4; ++j) {
                const int col = bn + wn + j * 16 + lr;
#pragma unroll
                for (int r = 0; r < 4; ++r) {
                    const int row = bm + wm + i * 16 + r0 + r;
                    Crm[(size_t)row * 1024 + col] = f2bf(acc[i][j][r] * scale);
                }
            }
        }
    }
}

// out[c*1024 + r] = bf16(in[r*1024 + c]) for the three 1024x1024 f32 weights.
__global__ __launch_bounds__(256)
void wtrans(const float* __restrict__ Qw, const float* __restrict__ Kw,
            const float* __restrict__ Vw, u16* __restrict__ Qt,
            u16* __restrict__ Kt, u16* __restrict__ Vt)
{
    __shared__ u16 tile[64][65];
    const float* in = (blockIdx.z == 0) ? Qw : (blockIdx.z == 1) ? Kw : Vw;
    u16* out        = (blockIdx.z == 0) ? Qt : (blockIdx.z == 1) ? Kt : Vt;
    const int r0 = blockIdx.y * 64;
    const int c0 = blockIdx.x * 64;
    const int tr = threadIdx.x >> 2;
    const int tq = threadIdx.x & 3;

    const float* p = in + (size_t)(r0 + tr) * 1024 + c0 + tq * 16;
#pragma unroll
    for (int i = 0; i < 16; i += 4) {
        float4 v = *(const float4*)(p + i);
        tile[tq * 16 + i + 0][tr] = f2bf(v.x);
        tile[tq * 16 + i + 1][tr] = f2bf(v.y);
        tile[tq * 16 + i + 2][tr] = f2bf(v.z);
        tile[tq * 16 + i + 3][tr] = f2bf(v.w);
    }
    __syncthreads();

    u16 tmp[16];
#pragma unroll
    for (int i = 0; i < 16; ++i) tmp[i] = tile[tr][tq * 16 + i];
    bf16x8 w0, w1;
#pragma unroll
    for (int j = 0; j < 8; ++j) { w0[j] = (short)tmp[j]; w1[j] = (short)tmp[8 + j]; }
    u16* o = out + (size_t)(c0 + tr) * 1024 + r0 + tq * 16;
    *(bf16x8*)o       = w0;
    *(bf16x8*)(o + 8) = w1;
}

// f32 -> bf16 for host (blocks 0..2047) and guests (2048..6143).
__global__ __launch_bounds__(256)
void cvt_inputs(const float* __restrict__ host, const float* __restrict__ guests,
                u16* __restrict__ host_bf, u16* __restrict__ guests_bf)
{
    int b = blockIdx.x;
    const float* in; u16* out;
    if (b < 2048) { in = host; out = host_bf; }
    else          { in = guests; out = guests_bf; b -= 2048; }
    const size_t i = ((size_t)b * 256 + threadIdx.x) * 8;
    float4 v0 = *(const float4*)(in + i);
    float4 v1 = *(const float4*)(in + i + 4);
    bf16x8 w;
    w[0] = (short)f2bf(v0.x); w[1] = (short)f2bf(v0.y);
    w[2] = (short)f2bf(v0.z); w[3] = (short)f2bf(v0.w);
    w[4] = (short)f2bf(v1.x); w[5] = (short)f2bf(v1.y);
    w[6] = (short)f2bf(v1.z); w[7] = (short)f2bf(v1.w);
    *(bf16x8*)(out + i) = w;
}

// out += p1 + p2
__global__ __launch_bounds__(256)
void add2_f32(float* __restrict__ out, const float* __restrict__ p1,
              const float* __restrict__ p2)
{
    const size_t i = ((size_t)blockIdx.x * 256 + threadIdx.x) * 4;
    float4 a = *(const float4*)(out + i);
    float4 b = *(const float4*)(p1 + i);
    float4 c = *(const float4*)(p2 + i);
    a.x += b.x + c.x; a.y += b.y + c.y; a.z += b.z + c.z; a.w += b.w + c.w;
    *(float4*)(out + i) = a;
}

// In-place row softmax over bf16 logits, one block per row of 8192.
__global__ __launch_bounds__(256)
void softmax_inplace(u16* __restrict__ att)
{
    const int tid = threadIdx.x;
    u16* p = att + (size_t)blockIdx.x * 8192;

    float x[32];
#pragma unroll
    for (int c = 0; c < 4; ++c) {
        bf16x8 v = *(const bf16x8*)(p + c * 2048 + tid * 8);
#pragma unroll
        for (int j = 0; j < 8; ++j) x[c * 8 + j] = bf2f((u16)v[j]);
    }

    float mx = -1e30f;
#pragma unroll
    for (int i = 0; i < 32; ++i) mx = fmaxf(mx, x[i]);
#pragma unroll
    for (int o = 32; o >= 1; o >>= 1) mx = fmaxf(mx, __shfl_xor(mx, o));

    __shared__ float red[8];
    const int wid = tid >> 6, lane = tid & 63;
    if (lane == 0) red[wid] = mx;
    __syncthreads();
    mx = fmaxf(fmaxf(red[0], red[1]), fmaxf(red[2], red[3]));

    float s = 0.f;
#pragma unroll
    for (int i = 0; i < 32; ++i) { x[i] = __expf(x[i] - mx); s += x[i]; }
#pragma unroll
    for (int o = 32; o >= 1; o >>= 1) s += __shfl_xor(s, o);
    if (lane == 0) red[4 + wid] = s;
    __syncthreads();
    s = red[4] + red[5] + red[6] + red[7];
    const float inv = 1.0f / s;

#pragma unroll
    for (int c = 0; c < 4; ++c) {
        bf16x8 w;
#pragma unroll
        for (int j = 0; j < 8; ++j) w[j] = (short)f2bf(x[c * 8 + j] * inv);
        *(bf16x8*)(p + c * 2048 + tid * 8) = w;
    }
}

extern "C" void kernel_launch(void* const* d_in, const int* in_sizes, int n_in,
                              void* d_out, int out_size, void* d_ws, size_t ws_size,
                              hipStream_t stream)
{
    const float* host   = (const float*)d_in[0];  // [4096][1024]
    const float* guests = (const float*)d_in[1];  // [8192][1024]
    const float* Qw     = (const float*)d_in[2];  // [1024][1024]
    const float* Kw     = (const float*)d_in[3];
    const float* Vw     = (const float*)d_in[4];
    float* out = (float*)d_out;                   // [4096][1024]

    char* ws = (char*)d_ws;
    // Lifetime-overlapped layout (peak 120 MB, proven in r5):
    //   [0..64)    att (ph 3-5)   | host_bf@0..8, guests_bf@8..24, W@24..30 (ph 1-2)
    //   [64..72)   query_bf (2-3) | part1 @ [64..80) (ph 5, over dead query/key)
    //   [72..88)   key_bf (2-3)
    //   [88..104)  value_t (2-5)
    //   [104..120) part2 (ph 5)
    u16* att       = (u16*)(ws);
    u16* host_bf   = (u16*)(ws);
    u16* guests_bf = (u16*)(ws + ( 8ull << 20));
    u16* Qt        = (u16*)(ws + (24ull << 20));
    u16* Kt        = (u16*)(ws + (26ull << 20));
    u16* Vt        = (u16*)(ws + (28ull << 20));
    u16* query_bf  = (u16*)(ws + (64ull << 20));
    u16* key_bf    = (u16*)(ws + (72ull << 20));
    u16* value_t   = (u16*)(ws + (88ull << 20));
    float* part1   = (float*)(ws + (64ull << 20));
    float* part2   = (float*)(ws + (104ull << 20));

    dim3 blk(256);

    // phase 1: dtype prep
    cvt_inputs<<<dim3(6144), blk, 0, stream>>>(host, guests, host_bf, guests_bf);
    wtrans<<<dim3(16, 16, 3), blk, 0, stream>>>(Qw, Kw, Vw, Qt, Kt, Vt);

    // phase 2: all projections (query pre-scaled by 1/32; value written transposed)
    proj_gemm<<<dim3(1280), blk, 0, stream>>>(host_bf, guests_bf, Qt, Kt, Vt,
                                              query_bf, key_bf, value_t);

    // phase 3: att = (q/32) . k  (256^2 8-phase)
    qkt256<<<dim3(512), dim3(512), 0, stream>>>(query_bf, key_bf, att);

    // phase 4: softmax rows in place
    softmax_inplace<<<dim3(4096), blk, 0, stream>>>(att);

    // phase 5: out = P @ V  (256^2 8-phase, splitK=3)
    pv256<<<dim3(192), dim3(512), 0, stream>>>(att, value_t, out, part1, part2);
    add2_f32<<<dim3(4096), blk, 0, stream>>>(out, part1, part2);
}

// Round 7
// 344.292 us; speedup vs baseline: 1.6119x; 1.0168x over previous
//
#include <hip/hip_runtime.h>
#include <stdint.h>

typedef float f32x4 __attribute__((ext_vector_type(4)));
typedef short bf16x8 __attribute__((ext_vector_type(8)));
typedef unsigned short u16;
typedef u16 u16x4 __attribute__((ext_vector_type(4)));

__device__ __forceinline__ u16 f2bf(float f) {
    union { float f; uint32_t u; } v; v.f = f;
    uint32_t r = v.u + 0x7FFFu + ((v.u >> 16) & 1u);
    return (u16)(r >> 16);
}
__device__ __forceinline__ float bf2f(u16 b) {
    union { uint32_t u; float f; } v; v.u = ((uint32_t)b) << 16;
    return v.f;
}

// async global->LDS, 16B/lane; LDS dest is wave-uniform base + lane*16.
__device__ __forceinline__ void gload16(u16* lds, const u16* g) {
    __builtin_amdgcn_global_load_lds(
        (const __attribute__((address_space(1))) void*)(uintptr_t)g,
        (__attribute__((address_space(3))) void*)(uint32_t)(uintptr_t)lds,
        16, 0, 0);
}

// XCD-aware chunked remap (bijective when nwg % 8 == 0).
__device__ __forceinline__ int xcd_map(int bid, int nwg) {
    return (bid & 7) * (nwg >> 3) + (bid >> 3);
}

#define BK 32

// ===========================================================================
// 256x256 8-phase GEMM core (plain-HIP port of the HK/m201 schedule).
// Verified in round 6 (bank conflicts 0, absmax unchanged).
// ===========================================================================
__device__ __forceinline__ void gemm256_core(
    const u16* __restrict__ A, const u16* __restrict__ Bt,
    int lda, int ldb, int bm, int bn, int kBeg, int nt,
    u16* lds, f32x4 (&acc)[8][4])
{
    const int tid  = threadIdx.x;
    const int lane = tid & 63;
    const int wid  = tid >> 6;
    const int lr   = lane & 15;
    const int kg   = lane >> 4;
    const int wr   = wid >> 2;   // 0..1
    const int wc   = wid & 3;    // 0..3

    const int sr = tid >> 3;                         // 0..63
    const int sc = ((tid & 7) ^ (sr & 7)) * 8;       // swizzled source col (u16)
    const u16* As = A  + (size_t)(bm + sr) * lda + kBeg + sc;
    const u16* Bs = Bt + (size_t)(bn + sr) * ldb + kBeg + sc;
    const int ldsW = wid * 512;                      // wave-uniform LDS base (u16)

    int arow[8], brow[4], kc[2];
#pragma unroll
    for (int m = 0; m < 8; ++m) arow[m] = wr * 8192 + (m * 16 + lr) * 64;
#pragma unroll
    for (int n = 0; n < 4; ++n)
        brow[n] = 16384 + (wc >> 1) * 8192 + ((wc & 1) * 64 + n * 16 + lr) * 64;
#pragma unroll
    for (int ks = 0; ks < 2; ++ks) kc[ks] = (ks * 32 + kg * 8) ^ ((lr & 7) * 8);

#define STG_A(q, h, t) do { \
        const u16* _s = As + (size_t)((h) * 128) * lda + (t) * 64; \
        gload16(lds + (q) * 32768 + (h) * 8192 + ldsW, _s); \
        gload16(lds + (q) * 32768 + (h) * 8192 + 4096 + ldsW, _s + (size_t)64 * lda); \
    } while (0)
#define STG_B(q, h, t) do { \
        const u16* _s = Bs + (size_t)((h) * 128) * ldb + (t) * 64; \
        gload16(lds + (q) * 32768 + 16384 + (h) * 8192 + ldsW, _s); \
        gload16(lds + (q) * 32768 + 16384 + (h) * 8192 + 4096 + ldsW, _s + (size_t)64 * ldb); \
    } while (0)

    // prologue: tile0 complete into buf0; tile1 B-halves in flight into buf1.
    STG_A(0, 0, 0); STG_A(0, 1, 0); STG_B(0, 0, 0); STG_B(0, 1, 0);
    STG_B(1, 0, 1); STG_B(1, 1, 1);
    asm volatile("s_waitcnt vmcnt(4)" ::: "memory");   // tile0 landed
    __builtin_amdgcn_s_barrier();

    bf16x8 fa[4][2], fb[4][2];
    for (int t = 0; t < nt; ++t) {
        const int p  = t & 1;
        const int pb = p * 32768;

        // -- phase 1: quadrant (m0-3, n0-1); read a0-3 + b0-1; stage Ah0(t+1)
#pragma unroll
        for (int m = 0; m < 4; ++m)
#pragma unroll
            for (int ks = 0; ks < 2; ++ks)
                fa[m][ks] = *(const bf16x8*)&lds[pb + arow[m] + kc[ks]];
#pragma unroll
        for (int n = 0; n < 2; ++n)
#pragma unroll
            for (int ks = 0; ks < 2; ++ks)
                fb[n][ks] = *(const bf16x8*)&lds[pb + brow[n] + kc[ks]];
        if (t + 1 < nt) STG_A(p ^ 1, 0, t + 1);
        __builtin_amdgcn_s_barrier();
        asm volatile("s_waitcnt lgkmcnt(0)" ::: "memory");
        __builtin_amdgcn_sched_barrier(0);
        __builtin_amdgcn_s_setprio(1);
#pragma unroll
        for (int ks = 0; ks < 2; ++ks)
#pragma unroll
            for (int m = 0; m < 4; ++m)
#pragma unroll
                for (int n = 0; n < 2; ++n)
                    acc[m][n] = __builtin_amdgcn_mfma_f32_16x16x32_bf16(fa[m][ks], fb[n][ks], acc[m][n], 0, 0, 0);
        __builtin_amdgcn_s_setprio(0);
        __builtin_amdgcn_s_barrier();

        // -- phase 2: quadrant (m0-3, n2-3); read b2-3; stage Ah1(t+1)
#pragma unroll
        for (int n = 2; n < 4; ++n)
#pragma unroll
            for (int ks = 0; ks < 2; ++ks)
                fb[n][ks] = *(const bf16x8*)&lds[pb + brow[n] + kc[ks]];
        if (t + 1 < nt) STG_A(p ^ 1, 1, t + 1);
        __builtin_amdgcn_s_barrier();
        asm volatile("s_waitcnt lgkmcnt(0)" ::: "memory");
        __builtin_amdgcn_sched_barrier(0);
        __builtin_amdgcn_s_setprio(1);
#pragma unroll
        for (int ks = 0; ks < 2; ++ks)
#pragma unroll
            for (int m = 0; m < 4; ++m)
#pragma unroll
                for (int n = 2; n < 4; ++n)
                    acc[m][n] = __builtin_amdgcn_mfma_f32_16x16x32_bf16(fa[m][ks], fb[n][ks], acc[m][n], 0, 0, 0);
        __builtin_amdgcn_s_setprio(0);
        __builtin_amdgcn_s_barrier();

        // -- phase 3: quadrant (m4-7, n0-1); read a4-7; stage Bh0(t+2)
#pragma unroll
        for (int m = 0; m < 4; ++m)
#pragma unroll
            for (int ks = 0; ks < 2; ++ks)
                fa[m][ks] = *(const bf16x8*)&lds[pb + arow[4 + m] + kc[ks]];
        if (t + 2 < nt) STG_B(p, 0, t + 2);
        __builtin_amdgcn_s_barrier();
        asm volatile("s_waitcnt lgkmcnt(0)" ::: "memory");
        __builtin_amdgcn_sched_barrier(0);
        __builtin_amdgcn_s_setprio(1);
#pragma unroll
        for (int ks = 0; ks < 2; ++ks)
#pragma unroll
            for (int m = 0; m < 4; ++m)
#pragma unroll
                for (int n = 0; n < 2; ++n)
                    acc[4 + m][n] = __builtin_amdgcn_mfma_f32_16x16x32_bf16(fa[m][ks], fb[n][ks], acc[4 + m][n], 0, 0, 0);
        __builtin_amdgcn_s_setprio(0);
        __builtin_amdgcn_s_barrier();

        // -- phase 4: quadrant (m4-7, n2-3); stage Bh1(t+2); counted vmcnt
        if (t + 2 < nt) STG_B(p, 1, t + 2);
        __builtin_amdgcn_s_barrier();
        __builtin_amdgcn_s_setprio(1);
#pragma unroll
        for (int ks = 0; ks < 2; ++ks)
#pragma unroll
            for (int m = 0; m < 4; ++m)
#pragma unroll
                for (int n = 2; n < 4; ++n)
                    acc[4 + m][n] = __builtin_amdgcn_mfma_f32_16x16x32_bf16(fa[m][ks], fb[n][ks], acc[4 + m][n], 0, 0, 0);
        __builtin_amdgcn_s_setprio(0);
        if (t + 2 < nt)      asm volatile("s_waitcnt vmcnt(4)" ::: "memory"); // tile t+1 landed
        else if (t + 1 < nt) asm volatile("s_waitcnt vmcnt(0)" ::: "memory"); // tail drain
        __builtin_amdgcn_s_barrier();
    }
#undef STG_A
#undef STG_B
}

// QK^T: att[q][m] = query . key, 256^2 tiles, C bf16 (scale folded into query).
__global__ __launch_bounds__(512, 2)
void qkt256(const u16* __restrict__ A, const u16* __restrict__ Bt,
            u16* __restrict__ C)
{
    __shared__ u16 lds[65536];
    const int swz = xcd_map(blockIdx.x, 512);
    const int bm = (swz >> 5) * 256;   // 16 m-tiles
    const int bn = (swz & 31) * 256;   // 32 n-tiles
    f32x4 acc[8][4];
#pragma unroll
    for (int m = 0; m < 8; ++m)
#pragma unroll
        for (int n = 0; n < 4; ++n) acc[m][n] = (f32x4){0.f, 0.f, 0.f, 0.f};
    gemm256_core(A, Bt, 1024, 1024, bm, bn, 0, 16, lds, acc);

    const int lane = threadIdx.x & 63, wid = threadIdx.x >> 6;
    const int lr = lane & 15, kg = lane >> 4, wr = wid >> 2, wc = wid & 3;
#pragma unroll
    for (int m = 0; m < 8; ++m)
#pragma unroll
        for (int n = 0; n < 4; ++n) {
            const int col = bn + wc * 64 + n * 16 + lr;
#pragma unroll
            for (int r = 0; r < 4; ++r) {
                const int row = bm + wr * 128 + m * 16 + kg * 4 + r;
                C[(size_t)row * 8192 + col] = f2bf(acc[m][n][r]);
            }
        }
}

// PV: out[q][d] = att . value_t^T, 256^2 tiles, runtime splitK (3 or 4).
// 128 K-tiles total; z-group g covers tiles [g*ntPerZ, ...); last group gets
// the remainder. z=0 -> C0(out), z=1..3 -> C1..C3 partials.
__global__ __launch_bounds__(512, 2)
void pv256(const u16* __restrict__ A, const u16* __restrict__ Bt,
           float* __restrict__ C0, float* __restrict__ C1,
           float* __restrict__ C2, float* __restrict__ C3,
           int ntPerZ, int lastZ)
{
    __shared__ u16 lds[65536];
    const int swz = xcd_map(blockIdx.x, gridDim.x);
    const int z   = swz >> 6;
    const int rem = swz & 63;
    const int bm  = (rem >> 2) * 256;  // 16 m-tiles
    const int bn  = (rem & 3) * 256;   // 4 n-tiles
    const int kBeg = z * ntPerZ * 64;
    const int nt   = (z == lastZ) ? (128 - lastZ * ntPerZ) : ntPerZ;
    float* Cv = (z == 0) ? C0 : (z == 1) ? C1 : (z == 2) ? C2 : C3;

    f32x4 acc[8][4];
#pragma unroll
    for (int m = 0; m < 8; ++m)
#pragma unroll
        for (int n = 0; n < 4; ++n) acc[m][n] = (f32x4){0.f, 0.f, 0.f, 0.f};
    gemm256_core(A, Bt, 8192, 8192, bm, bn, kBeg, nt, lds, acc);

    const int lane = threadIdx.x & 63, wid = threadIdx.x >> 6;
    const int lr = lane & 15, kg = lane >> 4, wr = wid >> 2, wc = wid & 3;
#pragma unroll
    for (int m = 0; m < 8; ++m)
#pragma unroll
        for (int n = 0; n < 4; ++n) {
            const int col = bn + wc * 64 + n * 16 + lr;
#pragma unroll
            for (int r = 0; r < 4; ++r) {
                const int row = bm + wr * 128 + m * 16 + kg * 4 + r;
                Cv[(size_t)row * 1024 + col] = acc[m][n][r];
            }
        }
}

// ---------------------------------------------------------------------------
// Merged projection GEMM (unchanged control, 128^2 m97-structure).
// ---------------------------------------------------------------------------
__global__ __launch_bounds__(256)
void proj_gemm(const u16* __restrict__ host_bf, const u16* __restrict__ guests_bf,
               const u16* __restrict__ Qt, const u16* __restrict__ Kt,
               const u16* __restrict__ Vt,
               u16* __restrict__ query_bf, u16* __restrict__ key_bf,
               u16* __restrict__ value_t)
{
    __shared__ u16 a_s[128 * BK];
    __shared__ u16 b_s[128 * BK];
    const int id = xcd_map(blockIdx.x, 1280);

    const u16 *A, *B; u16* Crm = nullptr; int bm, bn; int group;
    if (id < 256)      { group = 0; A = host_bf;   B = Qt; Crm = query_bf; bm = (id >> 3) * 128;         bn = (id & 7) * 128; }
    else if (id < 768) { group = 1; A = guests_bf; B = Kt; Crm = key_bf;   bm = ((id - 256) >> 3) * 128; bn = ((id - 256) & 7) * 128; }
    else               { group = 2; A = guests_bf; B = Vt; Crm = nullptr;  bm = ((id - 768) >> 3) * 128; bn = ((id - 768) & 7) * 128; }

    const int tid  = threadIdx.x;
    const int lane = tid & 63;
    const int wid  = tid >> 6;
    const int lr   = lane & 15;
    const int kg   = lane >> 4;
    const int wm   = (wid >> 1) * 64;
    const int wn   = (wid & 1) * 64;
    const int srow = tid >> 2;
    const int scol = (tid & 3) * 8;

    const u16* Ar0 = A + (size_t)(bm + srow) * 1024 + scol;
    const u16* Ar1 = A + (size_t)(bm + 64 + srow) * 1024 + scol;
    const u16* Br0 = B + (size_t)(bn + srow) * 1024 + scol;
    const u16* Br1 = B + (size_t)(bn + 64 + srow) * 1024 + scol;
    u16* a_d0 = a_s + wid * 512;
    u16* a_d1 = a_s + 2048 + wid * 512;
    u16* b_d0 = b_s + wid * 512;
    u16* b_d1 = b_s + 2048 + wid * 512;

    f32x4 acc[4][4];
#pragma unroll
    for (int i = 0; i < 4; ++i)
#pragma unroll
        for (int j = 0; j < 4; ++j)
            acc[i][j] = (f32x4){0.f, 0.f, 0.f, 0.f};

    for (int k0 = 0; k0 < 1024; k0 += BK) {
        __syncthreads();
        gload16(a_d0, Ar0 + k0);
        gload16(a_d1, Ar1 + k0);
        gload16(b_d0, Br0 + k0);
        gload16(b_d1, Br1 + k0);
        __syncthreads();

        bf16x8 af[4], bfr[4];
#pragma unroll
        for (int i = 0; i < 4; ++i)
            af[i] = *(const bf16x8*)&a_s[(wm + i * 16 + lr) * BK + kg * 8];
#pragma unroll
        for (int j = 0; j < 4; ++j)
            bfr[j] = *(const bf16x8*)&b_s[(wn + j * 16 + lr) * BK + kg * 8];
#pragma unroll
        for (int i = 0; i < 4; ++i)
#pragma unroll
            for (int j = 0; j < 4; ++j)
                acc[i][j] = __builtin_amdgcn_mfma_f32_16x16x32_bf16(af[i], bfr[j], acc[i][j], 0, 0, 0);
    }

    const int r0 = kg * 4;
    if (group == 2) {
#pragma unroll
        for (int i = 0; i < 4; ++i) {
#pragma unroll
            for (int j = 0; j < 4; ++j) {
                const int col = bn + wn + j * 16 + lr;
                const int row = bm + wm + i * 16 + r0;
                u16x4 w;
#pragma unroll
                for (int r = 0; r < 4; ++r) w[r] = f2bf(acc[i][j][r]);
                *(u16x4*)&value_t[(size_t)col * 8192 + row] = w;
            }
        }
    } else {
        const float scale = (group == 0) ? 0.03125f : 1.0f;
#pragma unroll
        for (int i = 0; i < 4; ++i) {
#pragma unroll
            for (int j = 0; j < 4; ++j) {
                const int col = bn + wn + j * 16 + lr;
#pragma unroll
                for (int r = 0; r < 4; ++r) {
                    const int row = bm + wm + i * 16 + r0 + r;
                    Crm[(size_t)row * 1024 + col] = f2bf(acc[i][j][r] * scale);
                }
            }
        }
    }
}

// Merged prep: blocks 0..6143 convert host/guests f32->bf16; blocks
// 6144..6911 transpose the three 1024x1024 weights to bf16 (64x64 tiles).
__global__ __launch_bounds__(256)
void prep(const float* __restrict__ host, const float* __restrict__ guests,
          const float* __restrict__ Qw, const float* __restrict__ Kw,
          const float* __restrict__ Vw,
          u16* __restrict__ host_bf, u16* __restrict__ guests_bf,
          u16* __restrict__ Qt, u16* __restrict__ Kt, u16* __restrict__ Vt)
{
    __shared__ u16 tile[64][65];
    int b = blockIdx.x;
    if (b < 6144) {
        const float* in; u16* out;
        if (b < 2048) { in = host; out = host_bf; }
        else          { in = guests; out = guests_bf; b -= 2048; }
        const size_t i = ((size_t)b * 256 + threadIdx.x) * 8;
        float4 v0 = *(const float4*)(in + i);
        float4 v1 = *(const float4*)(in + i + 4);
        bf16x8 w;
        w[0] = (short)f2bf(v0.x); w[1] = (short)f2bf(v0.y);
        w[2] = (short)f2bf(v0.z); w[3] = (short)f2bf(v0.w);
        w[4] = (short)f2bf(v1.x); w[5] = (short)f2bf(v1.y);
        w[6] = (short)f2bf(v1.z); w[7] = (short)f2bf(v1.w);
        *(bf16x8*)(out + i) = w;
        return;
    }
    b -= 6144;                         // 0..767
    const int zz = b >> 8;             // 0..2
    const int t8 = b & 255;
    const float* in = (zz == 0) ? Qw : (zz == 1) ? Kw : Vw;
    u16* out        = (zz == 0) ? Qt : (zz == 1) ? Kt : Vt;
    const int r0 = (t8 >> 4) * 64;
    const int c0 = (t8 & 15) * 64;
    const int tr = threadIdx.x >> 2;
    const int tq = threadIdx.x & 3;

    const float* p = in + (size_t)(r0 + tr) * 1024 + c0 + tq * 16;
#pragma unroll
    for (int i = 0; i < 16; i += 4) {
        float4 v = *(const float4*)(p + i);
        tile[tq * 16 + i + 0][tr] = f2bf(v.x);
        tile[tq * 16 + i + 1][tr] = f2bf(v.y);
        tile[tq * 16 + i + 2][tr] = f2bf(v.z);
        tile[tq * 16 + i + 3][tr] = f2bf(v.w);
    }
    __syncthreads();

    u16 tmp[16];
#pragma unroll
    for (int i = 0; i < 16; ++i) tmp[i] = tile[tr][tq * 16 + i];
    bf16x8 w0, w1;
#pragma unroll
    for (int j = 0; j < 8; ++j) { w0[j] = (short)tmp[j]; w1[j] = (short)tmp[8 + j]; }
    u16* o = out + (size_t)(c0 + tr) * 1024 + r0 + tq * 16;
    *(bf16x8*)o       = w0;
    *(bf16x8*)(o + 8) = w1;
}

// out += p1 + p2 (+ p3 if n3)
__global__ __launch_bounds__(256)
void addN(float* __restrict__ out, const float* __restrict__ p1,
          const float* __restrict__ p2, const float* __restrict__ p3, int n3)
{
    const size_t i = ((size_t)blockIdx.x * 256 + threadIdx.x) * 4;
    float4 a = *(const float4*)(out + i);
    float4 b = *(const float4*)(p1 + i);
    float4 c = *(const float4*)(p2 + i);
    a.x += b.x + c.x; a.y += b.y + c.y; a.z += b.z + c.z; a.w += b.w + c.w;
    if (n3) {
        float4 d = *(const float4*)(p3 + i);
        a.x += d.x; a.y += d.y; a.z += d.z; a.w += d.w;
    }
    *(float4*)(out + i) = a;
}

// In-place row softmax over bf16 logits, one block per row of 8192.
__global__ __launch_bounds__(256)
void softmax_inplace(u16* __restrict__ att)
{
    const int tid = threadIdx.x;
    u16* p = att + (size_t)blockIdx.x * 8192;

    float x[32];
#pragma unroll
    for (int c = 0; c < 4; ++c) {
        bf16x8 v = *(const bf16x8*)(p + c * 2048 + tid * 8);
#pragma unroll
        for (int j = 0; j < 8; ++j) x[c * 8 + j] = bf2f((u16)v[j]);
    }

    float mx = -1e30f;
#pragma unroll
    for (int i = 0; i < 32; ++i) mx = fmaxf(mx, x[i]);
#pragma unroll
    for (int o = 32; o >= 1; o >>= 1) mx = fmaxf(mx, __shfl_xor(mx, o));

    __shared__ float red[8];
    const int wid = tid >> 6, lane = tid & 63;
    if (lane == 0) red[wid] = mx;
    __syncthreads();
    mx = fmaxf(fmaxf(red[0], red[1]), fmaxf(red[2], red[3]));

    float s = 0.f;
#pragma unroll
    for (int i = 0; i < 32; ++i) { x[i] = __expf(x[i] - mx); s += x[i]; }
#pragma unroll
    for (int o = 32; o >= 1; o >>= 1) s += __shfl_xor(s, o);
    if (lane == 0) red[4 + wid] = s;
    __syncthreads();
    s = red[4] + red[5] + red[6] + red[7];
    const float inv = 1.0f / s;

#pragma unroll
    for (int c = 0; c < 4; ++c) {
        bf16x8 w;
#pragma unroll
        for (int j = 0; j < 8; ++j) w[j] = (short)f2bf(x[c * 8 + j] * inv);
        *(bf16x8*)(p + c * 2048 + tid * 8) = w;
    }
}

extern "C" void kernel_launch(void* const* d_in, const int* in_sizes, int n_in,
                              void* d_out, int out_size, void* d_ws, size_t ws_size,
                              hipStream_t stream)
{
    const float* host   = (const float*)d_in[0];  // [4096][1024]
    const float* guests = (const float*)d_in[1];  // [8192][1024]
    const float* Qw     = (const float*)d_in[2];  // [1024][1024]
    const float* Kw     = (const float*)d_in[3];
    const float* Vw     = (const float*)d_in[4];
    float* out = (float*)d_out;                   // [4096][1024]

    char* ws = (char*)d_ws;
    // Phase 1-2 temporaries always live inside [0..30), dead before att:
    u16* att       = (u16*)(ws);
    u16* host_bf   = (u16*)(ws);
    u16* guests_bf = (u16*)(ws + ( 8ull << 20));
    u16* Qt        = (u16*)(ws + (24ull << 20));
    u16* Kt        = (u16*)(ws + (26ull << 20));
    u16* Vt        = (u16*)(ws + (28ull << 20));

    // splitK=4 needs 128 MB of ws; fall back to round-6 splitK=3 otherwise.
    const bool big = ws_size >= (128ull << 20);
    u16 *query_bf, *key_bf, *value_t;
    float *part1, *part2, *part3;
    int ntPerZ, lastZ, pvGrid, n3;
    if (big) {
        // [0..64) att | [64..80) value_t | [80..88) query | [88..104) key
        // phase 5: part1 [80..96), part2 [96..112), part3 [112..128)
        value_t  = (u16*)(ws + (64ull  << 20));
        query_bf = (u16*)(ws + (80ull  << 20));
        key_bf   = (u16*)(ws + (88ull  << 20));
        part1    = (float*)(ws + (80ull  << 20));
        part2    = (float*)(ws + (96ull  << 20));
        part3    = (float*)(ws + (112ull << 20));
        ntPerZ = 32; lastZ = 3; pvGrid = 256; n3 = 1;
    } else {
        // round-6 layout (peak 120 MB)
        query_bf = (u16*)(ws + (64ull  << 20));
        key_bf   = (u16*)(ws + (72ull  << 20));
        value_t  = (u16*)(ws + (88ull  << 20));
        part1    = (float*)(ws + (64ull  << 20));
        part2    = (float*)(ws + (104ull << 20));
        part3    = part1;  // unused
        ntPerZ = 43; lastZ = 2; pvGrid = 192; n3 = 0;
    }

    dim3 blk(256);

    // phase 1: dtype prep (converts + weight transposes, one kernel)
    prep<<<dim3(6912), blk, 0, stream>>>(host, guests, Qw, Kw, Vw,
                                         host_bf, guests_bf, Qt, Kt, Vt);

    // phase 2: all projections (query pre-scaled by 1/32; value transposed)
    proj_gemm<<<dim3(1280), blk, 0, stream>>>(host_bf, guests_bf, Qt, Kt, Vt,
                                              query_bf, key_bf, value_t);

    // phase 3: att = (q/32) . k  (256^2 8-phase)
    qkt256<<<dim3(512), dim3(512), 0, stream>>>(query_bf, key_bf, att);

    // phase 4: softmax rows in place
    softmax_inplace<<<dim3(4096), blk, 0, stream>>>(att);

    // phase 5: out = P @ V  (256^2 8-phase, splitK=3 or 4)
    pv256<<<dim3(pvGrid), dim3(512), 0, stream>>>(att, value_t, out,
                                                  part1, part2, part3,
                                                  ntPerZ, lastZ);
    addN<<<dim3(4096), blk, 0, stream>>>(out, part1, part2, part3, n3);
}

// Round 8
// 336.485 us; speedup vs baseline: 1.6493x; 1.0232x over previous
//
#include <hip/hip_runtime.h>
#include <stdint.h>

typedef float f32x4 __attribute__((ext_vector_type(4)));
typedef short bf16x8 __attribute__((ext_vector_type(8)));
typedef unsigned short u16;
typedef u16 u16x4 __attribute__((ext_vector_type(4)));

__device__ __forceinline__ u16 f2bf(float f) {
    union { float f; uint32_t u; } v; v.f = f;
    uint32_t r = v.u + 0x7FFFu + ((v.u >> 16) & 1u);
    return (u16)(r >> 16);
}
__device__ __forceinline__ float bf2f(u16 b) {
    union { uint32_t u; float f; } v; v.u = ((uint32_t)b) << 16;
    return v.f;
}

// async global->LDS, 16B/lane; LDS dest is wave-uniform base + lane*16.
__device__ __forceinline__ void gload16(u16* lds, const u16* g) {
    __builtin_amdgcn_global_load_lds(
        (const __attribute__((address_space(1))) void*)(uintptr_t)g,
        (__attribute__((address_space(3))) void*)(uint32_t)(uintptr_t)lds,
        16, 0, 0);
}

// XCD-aware chunked remap (bijective when nwg % 8 == 0).
__device__ __forceinline__ int xcd_map(int bid, int nwg) {
    return (bid & 7) * (nwg >> 3) + (bid >> 3);
}

#define BK 32

// ===========================================================================
// 256x256 8-phase GEMM core (verified r6/r7: bank conflicts 0, refcheck'd).
// ===========================================================================
__device__ __forceinline__ void gemm256_core(
    const u16* __restrict__ A, const u16* __restrict__ Bt,
    int lda, int ldb, int bm, int bn, int kBeg, int nt,
    u16* lds, f32x4 (&acc)[8][4])
{
    const int tid  = threadIdx.x;
    const int lane = tid & 63;
    const int wid  = tid >> 6;
    const int lr   = lane & 15;
    const int kg   = lane >> 4;
    const int wr   = wid >> 2;   // 0..1
    const int wc   = wid & 3;    // 0..3

    const int sr = tid >> 3;                         // 0..63
    const int sc = ((tid & 7) ^ (sr & 7)) * 8;       // swizzled source col (u16)
    const u16* As = A  + (size_t)(bm + sr) * lda + kBeg + sc;
    const u16* Bs = Bt + (size_t)(bn + sr) * ldb + kBeg + sc;
    const int ldsW = wid * 512;                      // wave-uniform LDS base (u16)

    int arow[8], brow[4], kc[2];
#pragma unroll
    for (int m = 0; m < 8; ++m) arow[m] = wr * 8192 + (m * 16 + lr) * 64;
#pragma unroll
    for (int n = 0; n < 4; ++n)
        brow[n] = 16384 + (wc >> 1) * 8192 + ((wc & 1) * 64 + n * 16 + lr) * 64;
#pragma unroll
    for (int ks = 0; ks < 2; ++ks) kc[ks] = (ks * 32 + kg * 8) ^ ((lr & 7) * 8);

#define STG_A(q, h, t) do { \
        const u16* _s = As + (size_t)((h) * 128) * lda + (t) * 64; \
        gload16(lds + (q) * 32768 + (h) * 8192 + ldsW, _s); \
        gload16(lds + (q) * 32768 + (h) * 8192 + 4096 + ldsW, _s + (size_t)64 * lda); \
    } while (0)
#define STG_B(q, h, t) do { \
        const u16* _s = Bs + (size_t)((h) * 128) * ldb + (t) * 64; \
        gload16(lds + (q) * 32768 + 16384 + (h) * 8192 + ldsW, _s); \
        gload16(lds + (q) * 32768 + 16384 + (h) * 8192 + 4096 + ldsW, _s + (size_t)64 * ldb); \
    } while (0)

    // prologue: tile0 complete into buf0; tile1 B-halves in flight into buf1.
    STG_A(0, 0, 0); STG_A(0, 1, 0); STG_B(0, 0, 0); STG_B(0, 1, 0);
    STG_B(1, 0, 1); STG_B(1, 1, 1);
    asm volatile("s_waitcnt vmcnt(4)" ::: "memory");   // tile0 landed
    __builtin_amdgcn_s_barrier();

    bf16x8 fa[4][2], fb[4][2];
    for (int t = 0; t < nt; ++t) {
        const int p  = t & 1;
        const int pb = p * 32768;

        // -- phase 1: quadrant (m0-3, n0-1); read a0-3 + b0-1; stage Ah0(t+1)
#pragma unroll
        for (int m = 0; m < 4; ++m)
#pragma unroll
            for (int ks = 0; ks < 2; ++ks)
                fa[m][ks] = *(const bf16x8*)&lds[pb + arow[m] + kc[ks]];
#pragma unroll
        for (int n = 0; n < 2; ++n)
#pragma unroll
            for (int ks = 0; ks < 2; ++ks)
                fb[n][ks] = *(const bf16x8*)&lds[pb + brow[n] + kc[ks]];
        if (t + 1 < nt) STG_A(p ^ 1, 0, t + 1);
        __builtin_amdgcn_s_barrier();
        asm volatile("s_waitcnt lgkmcnt(0)" ::: "memory");
        __builtin_amdgcn_sched_barrier(0);
        __builtin_amdgcn_s_setprio(1);
#pragma unroll
        for (int ks = 0; ks < 2; ++ks)
#pragma unroll
            for (int m = 0; m < 4; ++m)
#pragma unroll
                for (int n = 0; n < 2; ++n)
                    acc[m][n] = __builtin_amdgcn_mfma_f32_16x16x32_bf16(fa[m][ks], fb[n][ks], acc[m][n], 0, 0, 0);
        __builtin_amdgcn_s_setprio(0);
        __builtin_amdgcn_s_barrier();

        // -- phase 2: quadrant (m0-3, n2-3); read b2-3; stage Ah1(t+1)
#pragma unroll
        for (int n = 2; n < 4; ++n)
#pragma unroll
            for (int ks = 0; ks < 2; ++ks)
                fb[n][ks] = *(const bf16x8*)&lds[pb + brow[n] + kc[ks]];
        if (t + 1 < nt) STG_A(p ^ 1, 1, t + 1);
        __builtin_amdgcn_s_barrier();
        asm volatile("s_waitcnt lgkmcnt(0)" ::: "memory");
        __builtin_amdgcn_sched_barrier(0);
        __builtin_amdgcn_s_setprio(1);
#pragma unroll
        for (int ks = 0; ks < 2; ++ks)
#pragma unroll
            for (int m = 0; m < 4; ++m)
#pragma unroll
                for (int n = 2; n < 4; ++n)
                    acc[m][n] = __builtin_amdgcn_mfma_f32_16x16x32_bf16(fa[m][ks], fb[n][ks], acc[m][n], 0, 0, 0);
        __builtin_amdgcn_s_setprio(0);
        __builtin_amdgcn_s_barrier();

        // -- phase 3: quadrant (m4-7, n0-1); read a4-7; stage Bh0(t+2)
#pragma unroll
        for (int m = 0; m < 4; ++m)
#pragma unroll
            for (int ks = 0; ks < 2; ++ks)
                fa[m][ks] = *(const bf16x8*)&lds[pb + arow[4 + m] + kc[ks]];
        if (t + 2 < nt) STG_B(p, 0, t + 2);
        __builtin_amdgcn_s_barrier();
        asm volatile("s_waitcnt lgkmcnt(0)" ::: "memory");
        __builtin_amdgcn_sched_barrier(0);
        __builtin_amdgcn_s_setprio(1);
#pragma unroll
        for (int ks = 0; ks < 2; ++ks)
#pragma unroll
            for (int m = 0; m < 4; ++m)
#pragma unroll
                for (int n = 0; n < 2; ++n)
                    acc[4 + m][n] = __builtin_amdgcn_mfma_f32_16x16x32_bf16(fa[m][ks], fb[n][ks], acc[4 + m][n], 0, 0, 0);
        __builtin_amdgcn_s_setprio(0);
        __builtin_amdgcn_s_barrier();

        // -- phase 4: quadrant (m4-7, n2-3); stage Bh1(t+2); counted vmcnt
        if (t + 2 < nt) STG_B(p, 1, t + 2);
        __builtin_amdgcn_s_barrier();
        __builtin_amdgcn_s_setprio(1);
#pragma unroll
        for (int ks = 0; ks < 2; ++ks)
#pragma unroll
            for (int m = 0; m < 4; ++m)
#pragma unroll
                for (int n = 2; n < 4; ++n)
                    acc[4 + m][n] = __builtin_amdgcn_mfma_f32_16x16x32_bf16(fa[m][ks], fb[n][ks], acc[4 + m][n], 0, 0, 0);
        __builtin_amdgcn_s_setprio(0);
        if (t + 2 < nt)      asm volatile("s_waitcnt vmcnt(4)" ::: "memory"); // tile t+1 landed
        else if (t + 1 < nt) asm volatile("s_waitcnt vmcnt(0)" ::: "memory"); // tail drain
        __builtin_amdgcn_s_barrier();
    }
#undef STG_A
#undef STG_B
}

// QK^T: att[q][m] = query . key, 256^2 tiles, C bf16 (scale folded into query).
__global__ __launch_bounds__(512, 2)
void qkt256(const u16* __restrict__ A, const u16* __restrict__ Bt,
            u16* __restrict__ C)
{
    __shared__ u16 lds[65536];
    const int swz = xcd_map(blockIdx.x, 512);
    const int bm = (swz >> 5) * 256;   // 16 m-tiles
    const int bn = (swz & 31) * 256;   // 32 n-tiles
    f32x4 acc[8][4];
#pragma unroll
    for (int m = 0; m < 8; ++m)
#pragma unroll
        for (int n = 0; n < 4; ++n) acc[m][n] = (f32x4){0.f, 0.f, 0.f, 0.f};
    gemm256_core(A, Bt, 1024, 1024, bm, bn, 0, 16, lds, acc);

    const int lane = threadIdx.x & 63, wid = threadIdx.x >> 6;
    const int lr = lane & 15, kg = lane >> 4, wr = wid >> 2, wc = wid & 3;
#pragma unroll
    for (int m = 0; m < 8; ++m)
#pragma unroll
        for (int n = 0; n < 4; ++n) {
            const int col = bn + wc * 64 + n * 16 + lr;
#pragma unroll
            for (int r = 0; r < 4; ++r) {
                const int row = bm + wr * 128 + m * 16 + kg * 4 + r;
                C[(size_t)row * 8192 + col] = f2bf(acc[m][n][r]);
            }
        }
}

// PV: out[q][d] = att . value_t^T, 256^2 tiles, splitK=4 (nt=32 uniform,
// grid 256 = one full round at 1 block/CU). z=0 -> out (f32);
// z=1..3 -> bf16 partials P1..P3.
__global__ __launch_bounds__(512, 2)
void pv256(const u16* __restrict__ A, const u16* __restrict__ Bt,
           float* __restrict__ C0, u16* __restrict__ P1,
           u16* __restrict__ P2, u16* __restrict__ P3)
{
    __shared__ u16 lds[65536];
    const int swz = xcd_map(blockIdx.x, 256);
    const int z   = swz >> 6;          // 0..3
    const int rem = swz & 63;
    const int bm  = (rem >> 2) * 256;  // 16 m-tiles
    const int bn  = (rem & 3) * 256;   // 4 n-tiles
    const int kBeg = z * 2048;

    f32x4 acc[8][4];
#pragma unroll
    for (int m = 0; m < 8; ++m)
#pragma unroll
        for (int n = 0; n < 4; ++n) acc[m][n] = (f32x4){0.f, 0.f, 0.f, 0.f};
    gemm256_core(A, Bt, 8192, 8192, bm, bn, kBeg, 32, lds, acc);

    const int lane = threadIdx.x & 63, wid = threadIdx.x >> 6;
    const int lr = lane & 15, kg = lane >> 4, wr = wid >> 2, wc = wid & 3;
    if (z == 0) {
#pragma unroll
        for (int m = 0; m < 8; ++m)
#pragma unroll
            for (int n = 0; n < 4; ++n) {
                const int col = bn + wc * 64 + n * 16 + lr;
#pragma unroll
                for (int r = 0; r < 4; ++r) {
                    const int row = bm + wr * 128 + m * 16 + kg * 4 + r;
                    C0[(size_t)row * 1024 + col] = acc[m][n][r];
                }
            }
    } else {
        u16* P = (z == 1) ? P1 : (z == 2) ? P2 : P3;
#pragma unroll
        for (int m = 0; m < 8; ++m)
#pragma unroll
            for (int n = 0; n < 4; ++n) {
                const int col = bn + wc * 64 + n * 16 + lr;
#pragma unroll
                for (int r = 0; r < 4; ++r) {
                    const int row = bm + wr * 128 + m * 16 + kg * 4 + r;
                    P[(size_t)row * 1024 + col] = f2bf(acc[m][n][r]);
                }
            }
    }
}

// ---------------------------------------------------------------------------
// Merged projection GEMM (unchanged control, 128^2 m97-structure).
// ---------------------------------------------------------------------------
__global__ __launch_bounds__(256)
void proj_gemm(const u16* __restrict__ host_bf, const u16* __restrict__ guests_bf,
               const u16* __restrict__ Qt, const u16* __restrict__ Kt,
               const u16* __restrict__ Vt,
               u16* __restrict__ query_bf, u16* __restrict__ key_bf,
               u16* __restrict__ value_t)
{
    __shared__ u16 a_s[128 * BK];
    __shared__ u16 b_s[128 * BK];
    const int id = xcd_map(blockIdx.x, 1280);

    const u16 *A, *B; u16* Crm = nullptr; int bm, bn; int group;
    if (id < 256)      { group = 0; A = host_bf;   B = Qt; Crm = query_bf; bm = (id >> 3) * 128;         bn = (id & 7) * 128; }
    else if (id < 768) { group = 1; A = guests_bf; B = Kt; Crm = key_bf;   bm = ((id - 256) >> 3) * 128; bn = ((id - 256) & 7) * 128; }
    else               { group = 2; A = guests_bf; B = Vt; Crm = nullptr;  bm = ((id - 768) >> 3) * 128; bn = ((id - 768) & 7) * 128; }

    const int tid  = threadIdx.x;
    const int lane = tid & 63;
    const int wid  = tid >> 6;
    const int lr   = lane & 15;
    const int kg   = lane >> 4;
    const int wm   = (wid >> 1) * 64;
    const int wn   = (wid & 1) * 64;
    const int srow = tid >> 2;
    const int scol = (tid & 3) * 8;

    const u16* Ar0 = A + (size_t)(bm + srow) * 1024 + scol;
    const u16* Ar1 = A + (size_t)(bm + 64 + srow) * 1024 + scol;
    const u16* Br0 = B + (size_t)(bn + srow) * 1024 + scol;
    const u16* Br1 = B + (size_t)(bn + 64 + srow) * 1024 + scol;
    u16* a_d0 = a_s + wid * 512;
    u16* a_d1 = a_s + 2048 + wid * 512;
    u16* b_d0 = b_s + wid * 512;
    u16* b_d1 = b_s + 2048 + wid * 512;

    f32x4 acc[4][4];
#pragma unroll
    for (int i = 0; i < 4; ++i)
#pragma unroll
        for (int j = 0; j < 4; ++j)
            acc[i][j] = (f32x4){0.f, 0.f, 0.f, 0.f};

    for (int k0 = 0; k0 < 1024; k0 += BK) {
        __syncthreads();
        gload16(a_d0, Ar0 + k0);
        gload16(a_d1, Ar1 + k0);
        gload16(b_d0, Br0 + k0);
        gload16(b_d1, Br1 + k0);
        __syncthreads();

        bf16x8 af[4], bfr[4];
#pragma unroll
        for (int i = 0; i < 4; ++i)
            af[i] = *(const bf16x8*)&a_s[(wm + i * 16 + lr) * BK + kg * 8];
#pragma unroll
        for (int j = 0; j < 4; ++j)
            bfr[j] = *(const bf16x8*)&b_s[(wn + j * 16 + lr) * BK + kg * 8];
#pragma unroll
        for (int i = 0; i < 4; ++i)
#pragma unroll
            for (int j = 0; j < 4; ++j)
                acc[i][j] = __builtin_amdgcn_mfma_f32_16x16x32_bf16(af[i], bfr[j], acc[i][j], 0, 0, 0);
    }

    const int r0 = kg * 4;
    if (group == 2) {
#pragma unroll
        for (int i = 0; i < 4; ++i) {
#pragma unroll
            for (int j = 0; j < 4; ++j) {
                const int col = bn + wn + j * 16 + lr;
                const int row = bm + wm + i * 16 + r0;
                u16x4 w;
#pragma unroll
                for (int r = 0; r < 4; ++r) w[r] = f2bf(acc[i][j][r]);
                *(u16x4*)&value_t[(size_t)col * 8192 + row] = w;
            }
        }
    } else {
        const float scale = (group == 0) ? 0.03125f : 1.0f;
#pragma unroll
        for (int i = 0; i < 4; ++i) {
#pragma unroll
            for (int j = 0; j < 4; ++j) {
                const int col = bn + wn + j * 16 + lr;
#pragma unroll
                for (int r = 0; r < 4; ++r) {
                    const int row = bm + wm + i * 16 + r0 + r;
                    Crm[(size_t)row * 1024 + col] = f2bf(acc[i][j][r] * scale);
                }
            }
        }
    }
}

// Merged prep: blocks 0..6143 convert host/guests f32->bf16; blocks
// 6144..6911 transpose the three 1024x1024 weights to bf16 (64x64 tiles).
__global__ __launch_bounds__(256)
void prep(const float* __restrict__ host, const float* __restrict__ guests,
          const float* __restrict__ Qw, const float* __restrict__ Kw,
          const float* __restrict__ Vw,
          u16* __restrict__ host_bf, u16* __restrict__ guests_bf,
          u16* __restrict__ Qt, u16* __restrict__ Kt, u16* __restrict__ Vt)
{
    __shared__ u16 tile[64][65];
    int b = blockIdx.x;
    if (b < 6144) {
        const float* in; u16* out;
        if (b < 2048) { in = host; out = host_bf; }
        else          { in = guests; out = guests_bf; b -= 2048; }
        const size_t i = ((size_t)b * 256 + threadIdx.x) * 8;
        float4 v0 = *(const float4*)(in + i);
        float4 v1 = *(const float4*)(in + i + 4);
        bf16x8 w;
        w[0] = (short)f2bf(v0.x); w[1] = (short)f2bf(v0.y);
        w[2] = (short)f2bf(v0.z); w[3] = (short)f2bf(v0.w);
        w[4] = (short)f2bf(v1.x); w[5] = (short)f2bf(v1.y);
        w[6] = (short)f2bf(v1.z); w[7] = (short)f2bf(v1.w);
        *(bf16x8*)(out + i) = w;
        return;
    }
    b -= 6144;                         // 0..767
    const int zz = b >> 8;             // 0..2
    const int t8 = b & 255;
    const float* in = (zz == 0) ? Qw : (zz == 1) ? Kw : Vw;
    u16* out        = (zz == 0) ? Qt : (zz == 1) ? Kt : Vt;
    const int r0 = (t8 >> 4) * 64;
    const int c0 = (t8 & 15) * 64;
    const int tr = threadIdx.x >> 2;
    const int tq = threadIdx.x & 3;

    const float* p = in + (size_t)(r0 + tr) * 1024 + c0 + tq * 16;
#pragma unroll
    for (int i = 0; i < 16; i += 4) {
        float4 v = *(const float4*)(p + i);
        tile[tq * 16 + i + 0][tr] = f2bf(v.x);
        tile[tq * 16 + i + 1][tr] = f2bf(v.y);
        tile[tq * 16 + i + 2][tr] = f2bf(v.z);
        tile[tq * 16 + i + 3][tr] = f2bf(v.w);
    }
    __syncthreads();

    u16 tmp[16];
#pragma unroll
    for (int i = 0; i < 16; ++i) tmp[i] = tile[tr][tq * 16 + i];
    bf16x8 w0, w1;
#pragma unroll
    for (int j = 0; j < 8; ++j) { w0[j] = (short)tmp[j]; w1[j] = (short)tmp[8 + j]; }
    u16* o = out + (size_t)(c0 + tr) * 1024 + r0 + tq * 16;
    *(bf16x8*)o       = w0;
    *(bf16x8*)(o + 8) = w1;
}

// out += bf2f(p1) + bf2f(p2) + bf2f(p3), 4 elems/thread.
__global__ __launch_bounds__(256)
void addN(float* __restrict__ out, const u16* __restrict__ p1,
          const u16* __restrict__ p2, const u16* __restrict__ p3)
{
    const size_t i = ((size_t)blockIdx.x * 256 + threadIdx.x) * 4;
    float4 a = *(const float4*)(out + i);
    u16x4 b = *(const u16x4*)(p1 + i);
    u16x4 c = *(const u16x4*)(p2 + i);
    u16x4 d = *(const u16x4*)(p3 + i);
    a.x += bf2f(b[0]) + bf2f(c[0]) + bf2f(d[0]);
    a.y += bf2f(b[1]) + bf2f(c[1]) + bf2f(d[1]);
    a.z += bf2f(b[2]) + bf2f(c[2]) + bf2f(d[2]);
    a.w += bf2f(b[3]) + bf2f(c[3]) + bf2f(d[3]);
    *(float4*)(out + i) = a;
}

// In-place row softmax over bf16 logits, one block per row of 8192.
__global__ __launch_bounds__(256)
void softmax_inplace(u16* __restrict__ att)
{
    const int tid = threadIdx.x;
    u16* p = att + (size_t)blockIdx.x * 8192;

    float x[32];
#pragma unroll
    for (int c = 0; c < 4; ++c) {
        bf16x8 v = *(const bf16x8*)(p + c * 2048 + tid * 8);
#pragma unroll
        for (int j = 0; j < 8; ++j) x[c * 8 + j] = bf2f((u16)v[j]);
    }

    float mx = -1e30f;
#pragma unroll
    for (int i = 0; i < 32; ++i) mx = fmaxf(mx, x[i]);
#pragma unroll
    for (int o = 32; o >= 1; o >>= 1) mx = fmaxf(mx, __shfl_xor(mx, o));

    __shared__ float red[8];
    const int wid = tid >> 6, lane = tid & 63;
    if (lane == 0) red[wid] = mx;
    __syncthreads();
    mx = fmaxf(fmaxf(red[0], red[1]), fmaxf(red[2], red[3]));

    float s = 0.f;
#pragma unroll
    for (int i = 0; i < 32; ++i) { x[i] = __expf(x[i] - mx); s += x[i]; }
#pragma unroll
    for (int o = 32; o >= 1; o >>= 1) s += __shfl_xor(s, o);
    if (lane == 0) red[4 + wid] = s;
    __syncthreads();
    s = red[4] + red[5] + red[6] + red[7];
    const float inv = 1.0f / s;

#pragma unroll
    for (int c = 0; c < 4; ++c) {
        bf16x8 w;
#pragma unroll
        for (int j = 0; j < 8; ++j) w[j] = (short)f2bf(x[c * 8 + j] * inv);
        *(bf16x8*)(p + c * 2048 + tid * 8) = w;
    }
}

extern "C" void kernel_launch(void* const* d_in, const int* in_sizes, int n_in,
                              void* d_out, int out_size, void* d_ws, size_t ws_size,
                              hipStream_t stream)
{
    const float* host   = (const float*)d_in[0];  // [4096][1024]
    const float* guests = (const float*)d_in[1];  // [8192][1024]
    const float* Qw     = (const float*)d_in[2];  // [1024][1024]
    const float* Kw     = (const float*)d_in[3];
    const float* Vw     = (const float*)d_in[4];
    float* out = (float*)d_out;                   // [4096][1024]

    char* ws = (char*)d_ws;
    // Lifetime-overlapped layout (peak 104 MB):
    //   [0..64)   att (ph 3-5)   | host_bf@0..8, guests_bf@8..24, W@24..30 (ph 1-2)
    //   [64..80)  value_t (2-5)
    //   [80..88)  query_bf (2-3) | part1 bf16 (ph 5)
    //   [88..96)  key_bf lo      | part2 bf16 (ph 5)
    //   [96..104) key_bf hi      | part3 bf16 (ph 5)
    u16* att       = (u16*)(ws);
    u16* host_bf   = (u16*)(ws);
    u16* guests_bf = (u16*)(ws + ( 8ull << 20));
    u16* Qt        = (u16*)(ws + (24ull << 20));
    u16* Kt        = (u16*)(ws + (26ull << 20));
    u16* Vt        = (u16*)(ws + (28ull << 20));
    u16* value_t   = (u16*)(ws + (64ull << 20));
    u16* query_bf  = (u16*)(ws + (80ull << 20));
    u16* key_bf    = (u16*)(ws + (88ull << 20));
    u16* part1     = (u16*)(ws + (80ull << 20));
    u16* part2     = (u16*)(ws + (88ull << 20));
    u16* part3     = (u16*)(ws + (96ull << 20));

    dim3 blk(256);

    // phase 1: dtype prep (converts + weight transposes, one kernel)
    prep<<<dim3(6912), blk, 0, stream>>>(host, guests, Qw, Kw, Vw,
                                         host_bf, guests_bf, Qt, Kt, Vt);

    // phase 2: all projections (query pre-scaled by 1/32; value transposed)
    proj_gemm<<<dim3(1280), blk, 0, stream>>>(host_bf, guests_bf, Qt, Kt, Vt,
                                              query_bf, key_bf, value_t);

    // phase 3: att = (q/32) . k  (256^2 8-phase)
    qkt256<<<dim3(512), dim3(512), 0, stream>>>(query_bf, key_bf, att);

    // phase 4: softmax rows in place
    softmax_inplace<<<dim3(4096), blk, 0, stream>>>(att);

    // phase 5: out = P @ V  (256^2 8-phase, splitK=4, bf16 partials)
    pv256<<<dim3(256), dim3(512), 0, stream>>>(att, value_t, out,
                                               part1, part2, part3);
    addN<<<dim3(4096), blk, 0, stream>>>(out, part1, part2, part3);
}